// Round 2
// baseline (1120.526 us; speedup 1.0000x reference)
//
#include <hip/hip_runtime.h>
#include <hip/hip_bf16.h>
#include <math.h>

typedef __bf16 bf16;
typedef __bf16 bf16x4 __attribute__((ext_vector_type(4)));
typedef __bf16 bf16x8 __attribute__((ext_vector_type(8)));
typedef float  f32x4  __attribute__((ext_vector_type(4)));

typedef __attribute__((address_space(1))) void gvoid_t;
typedef __attribute__((address_space(3))) void lvoid_t;

static __device__ __forceinline__ void gload16(const void* g, void* l) {
  // async global->LDS, 16B per lane; LDS dest must be wave-uniform (HW adds lane*16)
  __builtin_amdgcn_global_load_lds((gvoid_t*)g, (lvoid_t*)l, 16, 0, 0);
}

// ---------------------------------------------------------------- converts
__global__ __launch_bounds__(256) void cvt_bf16(const float* __restrict__ in,
                                                bf16* __restrict__ out, int n8) {
  int i = blockIdx.x * 256 + threadIdx.x;
  if (i >= n8) return;
  const float4* p = (const float4*)(in + (size_t)i * 8);
  float4 v0 = p[0], v1 = p[1];
  bf16x8 o;
  o[0] = (bf16)v0.x; o[1] = (bf16)v0.y; o[2] = (bf16)v0.z; o[3] = (bf16)v0.w;
  o[4] = (bf16)v1.x; o[5] = (bf16)v1.y; o[6] = (bf16)v1.z; o[7] = (bf16)v1.w;
  *(bf16x8*)(out + (size_t)i * 8) = o;
}

// W [K][N] fp32 -> Wt [N][K] bf16 (32x32 LDS tiles)
__global__ __launch_bounds__(256) void tcvt(const float* __restrict__ W,
                                            bf16* __restrict__ Wt, int K, int N) {
  __shared__ float t[32][33];
  const int tid = threadIdx.x;
  const int r = tid >> 3, c4 = (tid & 7) * 4;
  const size_t grow = (size_t)(blockIdx.y * 32 + r);
  float4 v = *(const float4*)(W + grow * N + blockIdx.x * 32 + c4);
  t[r][c4 + 0] = v.x; t[r][c4 + 1] = v.y; t[r][c4 + 2] = v.z; t[r][c4 + 3] = v.w;
  __syncthreads();
  bf16x4 o = { (bf16)t[c4 + 0][r], (bf16)t[c4 + 1][r], (bf16)t[c4 + 2][r], (bf16)t[c4 + 3][r] };
  *(bf16x4*)(Wt + (size_t)(blockIdx.x * 32 + r) * K + blockIdx.y * 32 + c4) = o;
}

// ---------------------------------------------------------------- GEMM (NT)
// C[M][N] = A[M][K] * Bt[N][K]^T ; 128x128 tile, BK=64, 4 waves, m97 structure
template <typename OutT>
__global__ __launch_bounds__(256) void gemm_bt(const bf16* __restrict__ A,
                                               const bf16* __restrict__ Bt,
                                               OutT* __restrict__ C,
                                               int N, int K) {
  __shared__ bf16 As[128 * 64];
  __shared__ bf16 Bs[128 * 64];
  const int tid = threadIdx.x;
  const int wid = tid >> 6, lane = tid & 63;
  const int g = lane >> 4, c = lane & 15;
  const int brow = blockIdx.y * 128, bcol = blockIdx.x * 128;
  const int wr = (wid >> 1) * 64, wc = (wid & 1) * 64;
  f32x4 acc[4][4] = {};

  for (int k0 = 0; k0 < K; k0 += 64) {
#pragma unroll
    for (int i = 0; i < 4; ++i) {
      const int off = i * 4096 + tid * 16;       // byte offset in 16KB tile
      const int row = off >> 7, colb = off & 127;
      gload16((const char*)A + ((size_t)(brow + row) * K + k0) * 2 + colb,
              (char*)As + i * 4096 + wid * 1024);
      gload16((const char*)Bt + ((size_t)(bcol + row) * K + k0) * 2 + colb,
              (char*)Bs + i * 4096 + wid * 1024);
    }
    __syncthreads();   // compiler drains vmcnt before barrier
#pragma unroll
    for (int ks = 0; ks < 2; ++ks) {
      bf16x8 af[4], bfr[4];
#pragma unroll
      for (int t = 0; t < 4; ++t) {
        af[t]  = *(const bf16x8*)(As + (wr + t * 16 + c) * 64 + ks * 32 + g * 8);
        bfr[t] = *(const bf16x8*)(Bs + (wc + t * 16 + c) * 64 + ks * 32 + g * 8);
      }
#pragma unroll
      for (int mt = 0; mt < 4; ++mt)
#pragma unroll
        for (int nt = 0; nt < 4; ++nt)
          acc[mt][nt] = __builtin_amdgcn_mfma_f32_16x16x32_bf16(af[mt], bfr[nt], acc[mt][nt], 0, 0, 0);
    }
    __syncthreads();
  }
#pragma unroll
  for (int mt = 0; mt < 4; ++mt)
#pragma unroll
    for (int nt = 0; nt < 4; ++nt)
#pragma unroll
      for (int r = 0; r < 4; ++r) {
        const int row = brow + wr + mt * 16 + 4 * g + r;
        const int col = bcol + wc + nt * 16 + c;
        C[(size_t)row * N + col] = (OutT)acc[mt][nt][r];
      }
}

// ------------------------------------------- RMSNorm + RoPE epilogues
// q in-place: [4096][24*128], pos = row % 2048
__global__ __launch_bounds__(256) void nrope_q(bf16* __restrict__ q,
                                               const float* __restrict__ gw,
                                               const float* __restrict__ cache) {
  const int w = blockIdx.x * 4 + (threadIdx.x >> 6);
  const int lane = threadIdx.x & 63;
  const int row = w / 24, head = w % 24;
  const int pos = row & 2047;
  bf16* p = q + (size_t)row * 3072 + head * 128;
  float x1 = (float)p[lane], x2 = (float)p[64 + lane];
  float ss = x1 * x1 + x2 * x2;
#pragma unroll
  for (int m = 32; m; m >>= 1) ss += __shfl_xor(ss, m);
  const float inv = rsqrtf(ss * (1.0f / 128.0f) + 1e-6f);
  const float xn1 = x1 * inv * gw[lane], xn2 = x2 * inv * gw[64 + lane];
  const float cs = cache[pos * 128 + lane], sn = cache[pos * 128 + 64 + lane];
  p[lane]      = (bf16)(xn1 * cs - xn2 * sn);
  p[64 + lane] = (bf16)(xn2 * cs + xn1 * sn);
}

// k/tk: src [B*S][8*128] -> kf [b*8+hkv][2560][128] at key_off+s, with norm+rope
__global__ __launch_bounds__(256) void nrope_k(const bf16* __restrict__ src,
                                               bf16* __restrict__ kf,
                                               const float* __restrict__ gw,
                                               const float* __restrict__ cache,
                                               int S, int key_off) {
  const int w = blockIdx.x * 4 + (threadIdx.x >> 6);
  const int lane = threadIdx.x & 63;
  const int row = w >> 3, hkv = w & 7;
  const int b = row / S, s = row % S;
  const bf16* p = src + (size_t)row * 1024 + hkv * 128;
  float x1 = (float)p[lane], x2 = (float)p[64 + lane];
  float ss = x1 * x1 + x2 * x2;
#pragma unroll
  for (int m = 32; m; m >>= 1) ss += __shfl_xor(ss, m);
  const float inv = rsqrtf(ss * (1.0f / 128.0f) + 1e-6f);
  const float xn1 = x1 * inv * gw[lane], xn2 = x2 * inv * gw[64 + lane];
  const float cs = cache[s * 128 + lane], sn = cache[s * 128 + 64 + lane];
  bf16* o = kf + ((size_t)(b * 8 + hkv) * 2560 + key_off + s) * 128;
  o[lane]      = (bf16)(xn1 * cs - xn2 * sn);
  o[64 + lane] = (bf16)(xn2 * cs + xn1 * sn);
}

// v/tv: src [B*S][8*128] -> vt [b*8+hkv][128][2560] (transposed), 32x32 LDS tiles
__global__ __launch_bounds__(256) void transpose_v(const bf16* __restrict__ src,
                                                   bf16* __restrict__ vtp,
                                                   int S, int key_off) {
  __shared__ bf16 t[32][33];
  const int tid = threadIdx.x;
  const int bh = blockIdx.z;       // b*8+hkv
  const int b = bh >> 3, hkv = bh & 7;
  const int s0 = blockIdx.x * 32, d0 = blockIdx.y * 32;
  const int r = tid >> 3, c4 = (tid & 7) * 4;
  bf16x4 v = *(const bf16x4*)(src + (size_t)(b * S + s0 + r) * 1024 + hkv * 128 + d0 + c4);
  t[r][c4 + 0] = v[0]; t[r][c4 + 1] = v[1]; t[r][c4 + 2] = v[2]; t[r][c4 + 3] = v[3];
  __syncthreads();
  bf16x4 o = { t[c4 + 0][r], t[c4 + 1][r], t[c4 + 2][r], t[c4 + 3][r] };
  *(bf16x4*)(vtp + ((size_t)bh * 128 + d0 + r) * 2560 + key_off + s0 + c4) = o;
}

// ---------------------------------------------------------------- attention
// grid (16, 24, 2): 128 q per block, 4 waves x 32 q; GQA hkv = h/3
__global__ __launch_bounds__(256) void attn_kernel(const bf16* __restrict__ qf,   // [4096][3072]
                                                   const bf16* __restrict__ kf,   // [16][2560][128]
                                                   const bf16* __restrict__ vtp,  // [16][128][2560]
                                                   bf16* __restrict__ attnb) {    // [4096][3072]
  __shared__ bf16 osm[4][32 * 128];
  const int tid = threadIdx.x;
  const int wid = tid >> 6, lane = tid & 63;
  const int g = lane >> 4, c = lane & 15;
  const int h = blockIdx.y, b = blockIdx.z;
  const int q0 = blockIdx.x * 128 + wid * 32;
  const int hkv = h / 3;
  const size_t kbase = (size_t)(b * 8 + hkv) * 2560 * 128;
  const size_t vbase = (size_t)(b * 8 + hkv) * 128 * 2560;

  bf16x8 qfrag[2][4];
#pragma unroll
  for (int qt = 0; qt < 2; ++qt) {
    const size_t qrow = (size_t)(b * 2048 + q0 + qt * 16 + c) * 3072 + h * 128;
#pragma unroll
    for (int kc = 0; kc < 4; ++kc)
      qfrag[qt][kc] = *(const bf16x8*)(qf + qrow + kc * 32 + g * 8);
  }

  f32x4 ot[2][8] = {};
  float mrun[2] = { -__builtin_inff(), -__builtin_inff() };
  float lsum[2] = { 0.f, 0.f };
  const float sc = 0.08838834764831845f;   // 1/sqrt(128)

  for (int key0 = 0; key0 < 2560; key0 += 32) {
    // swapped QK^T: S^T = mfma(K, Q); lane holds S[q=c][key0 + 4g+r] (tile0) / +16 (tile1)
    f32x4 s[2][2] = {};
#pragma unroll
    for (int kc = 0; kc < 4; ++kc) {
      bf16x8 a0 = *(const bf16x8*)(kf + kbase + (size_t)(key0 + c) * 128 + kc * 32 + g * 8);
      bf16x8 a1 = *(const bf16x8*)(kf + kbase + (size_t)(key0 + 16 + c) * 128 + kc * 32 + g * 8);
#pragma unroll
      for (int qt = 0; qt < 2; ++qt) {
        s[qt][0] = __builtin_amdgcn_mfma_f32_16x16x32_bf16(a0, qfrag[qt][kc], s[qt][0], 0, 0, 0);
        s[qt][1] = __builtin_amdgcn_mfma_f32_16x16x32_bf16(a1, qfrag[qt][kc], s[qt][1], 0, 0, 0);
      }
    }
    bf16x8 vfrag[8];
#pragma unroll
    for (int dt = 0; dt < 8; ++dt)
      vfrag[dt] = *(const bf16x8*)(vtp + vbase + (size_t)(dt * 16 + c) * 2560 + key0 + g * 8);

#pragma unroll
    for (int qt = 0; qt < 2; ++qt) {
      float p0[4], p1[4];
      float tmax = -__builtin_inff();
#pragma unroll
      for (int r = 0; r < 4; ++r) {
        p0[r] = s[qt][0][r] * sc;
        p1[r] = s[qt][1][r] * sc;
        tmax = fmaxf(tmax, fmaxf(p0[r], p1[r]));
      }
      tmax = fmaxf(tmax, __shfl_xor(tmax, 16));
      tmax = fmaxf(tmax, __shfl_xor(tmax, 32));
      const float mnew = fmaxf(mrun[qt], tmax);
      const float alpha = __expf(mrun[qt] - mnew);
      float psum = 0.f;
#pragma unroll
      for (int r = 0; r < 4; ++r) {
        p0[r] = __expf(p0[r] - mnew);
        p1[r] = __expf(p1[r] - mnew);
        psum += p0[r] + p1[r];
      }
      psum += __shfl_xor(psum, 16);
      psum += __shfl_xor(psum, 32);
      lsum[qt] = lsum[qt] * alpha + psum;
      mrun[qt] = mnew;
      if (__any(alpha != 1.0f)) {
#pragma unroll
        for (int dt = 0; dt < 8; ++dt)
#pragma unroll
          for (int r = 0; r < 4; ++r) ot[qt][dt][r] *= alpha;
      }
      // redistribute P to PV B-frag: lane needs P[q=c][key = 8g+j]
      const int srcA = (2 * (g & 1)) * 16 + c;
      const int srcB = srcA + 16;
      const bool t1 = (g >= 2);
      bf16x8 pf;
#pragma unroll
      for (int r = 0; r < 4; ++r) {
        float a0v = __shfl(p0[r], srcA), a1v = __shfl(p1[r], srcA);
        pf[r] = (bf16)(t1 ? a1v : a0v);
        float b0v = __shfl(p0[r], srcB), b1v = __shfl(p1[r], srcB);
        pf[4 + r] = (bf16)(t1 ? b1v : b0v);
      }
#pragma unroll
      for (int dt = 0; dt < 8; ++dt)
        ot[qt][dt] = __builtin_amdgcn_mfma_f32_16x16x32_bf16(vfrag[dt], pf, ot[qt][dt], 0, 0, 0);
    }
  }

  // O^T[d][q] -> LDS [q][d] -> coalesced global
#pragma unroll
  for (int qt = 0; qt < 2; ++qt) {
    const float inv = 1.0f / lsum[qt];
#pragma unroll
    for (int dt = 0; dt < 8; ++dt)
#pragma unroll
      for (int r = 0; r < 4; ++r)
        osm[wid][(qt * 16 + c) * 128 + dt * 16 + 4 * g + r] = (bf16)(ot[qt][dt][r] * inv);
  }
  __syncthreads();
#pragma unroll
  for (int it = 0; it < 8; ++it) {
    const int off = it * 1024 + lane * 16;    // byte in 8KB tile
    const int qrow = off >> 8, colb = off & 255;
    bf16x8 v = *(const bf16x8*)((const char*)&osm[wid][0] + off);
    *(bf16x8*)((char*)attnb + ((size_t)(b * 2048 + q0 + qrow) * 3072 + h * 128) * 2 + colb) = v;
  }
}

// ---------------------------------------------------------------- launcher
extern "C" void kernel_launch(void* const* d_in, const int* in_sizes, int n_in,
                              void* d_out, int out_size, void* d_ws, size_t ws_size,
                              hipStream_t stream) {
  const float* hs     = (const float*)d_in[0];
  const float* ehs    = (const float*)d_in[1];
  const float* Wq     = (const float*)d_in[2];
  const float* Wk     = (const float*)d_in[3];
  const float* Wv     = (const float*)d_in[4];
  const float* Wak    = (const float*)d_in[5];
  const float* Wav    = (const float*)d_in[6];
  const float* Wo     = (const float*)d_in[7];
  const float* gq     = (const float*)d_in[8];
  const float* gk     = (const float*)d_in[9];
  const float* gak    = (const float*)d_in[10];
  const float* icache = (const float*)d_in[11];
  const float* tcache = (const float*)d_in[12];

  char* ws = (char*)d_ws;
  bf16* hsb   = (bf16*)(ws + 0);            // 25.2MB, reused as attnb after q/k/v GEMMs
  bf16* ehsb  = (bf16*)(ws + 25165824);     // 6.3MB
  bf16* Wqt   = (bf16*)(ws + 31457280);     // 18.9MB
  bf16* Wkt   = (bf16*)(ws + 50331648);     // 6.3MB  (region Wkt..Wavt reused as qraw)
  bf16* Wvt   = (bf16*)(ws + 56623104);     // 6.3MB
  bf16* Wakt  = (bf16*)(ws + 62914560);     // 6.3MB
  bf16* Wavt  = (bf16*)(ws + 69206016);     // 6.3MB
  bf16* Wot   = (bf16*)(ws + 75497472);     // 18.9MB
  bf16* kraw  = (bf16*)(ws + 94371840);     // 8.4MB
  bf16* vraw  = (bf16*)(ws + 102760448);    // 8.4MB
  bf16* tkraw = (bf16*)(ws + 111149056);    // 2.1MB
  bf16* tvraw = (bf16*)(ws + 113246208);    // 2.1MB
  bf16* kf    = (bf16*)(ws + 115343360);    // 10.5MB joint K [16][2560][128]
  bf16* vt    = (bf16*)(ws + 125829120);    // 10.5MB joint V^T [16][128][2560]
  bf16* qraw  = (bf16*)(ws + 50331648);     // aliases Wkt..Wavt (dead by then)
  bf16* attnb = hsb;                        // aliases hsb (dead after q/k/v GEMMs)
  // total ws footprint: 136,314,880 bytes

  cvt_bf16<<<6144, 256, 0, stream>>>(hs, hsb, 1572864);
  cvt_bf16<<<1536, 256, 0, stream>>>(ehs, ehsb, 393216);
  tcvt<<<dim3(96, 96), 256, 0, stream>>>(Wq,  Wqt,  3072, 3072);
  tcvt<<<dim3(32, 96), 256, 0, stream>>>(Wk,  Wkt,  3072, 1024);
  tcvt<<<dim3(32, 96), 256, 0, stream>>>(Wv,  Wvt,  3072, 1024);
  tcvt<<<dim3(32, 96), 256, 0, stream>>>(Wak, Wakt, 3072, 1024);
  tcvt<<<dim3(32, 96), 256, 0, stream>>>(Wav, Wavt, 3072, 1024);
  tcvt<<<dim3(96, 96), 256, 0, stream>>>(Wo,  Wot,  3072, 3072);

  // k/v/tk/tv first (their weights die), then q overwrites Wkt..Wavt
  gemm_bt<bf16><<<dim3(8, 32), 256, 0, stream>>>(hsb,  Wkt,  kraw,  1024, 3072);
  gemm_bt<bf16><<<dim3(8, 32), 256, 0, stream>>>(hsb,  Wvt,  vraw,  1024, 3072);
  gemm_bt<bf16><<<dim3(8, 8),  256, 0, stream>>>(ehsb, Wakt, tkraw, 1024, 3072);
  gemm_bt<bf16><<<dim3(8, 8),  256, 0, stream>>>(ehsb, Wavt, tvraw, 1024, 3072);
  gemm_bt<bf16><<<dim3(24, 32), 256, 0, stream>>>(hsb, Wqt,  qraw,  3072, 3072);

  nrope_q<<<24576, 256, 0, stream>>>(qraw, gq, icache);
  nrope_k<<<8192, 256, 0, stream>>>(kraw,  kf, gk,  icache, 2048, 0);
  nrope_k<<<2048, 256, 0, stream>>>(tkraw, kf, gak, tcache, 512,  2048);
  transpose_v<<<dim3(64, 4, 16), 256, 0, stream>>>(vraw,  vt, 2048, 0);
  transpose_v<<<dim3(16, 4, 16), 256, 0, stream>>>(tvraw, vt, 512,  2048);

  attn_kernel<<<dim3(16, 24, 2), 256, 0, stream>>>(qraw, kf, vt, attnb);

  gemm_bt<float><<<dim3(24, 32), 256, 0, stream>>>(attnb, Wot, (float*)d_out, 3072, 3072);
}

// Round 4
// 997.376 us; speedup vs baseline: 1.1235x; 1.1235x over previous
//
#include <hip/hip_runtime.h>
#include <hip/hip_bf16.h>
#include <math.h>

typedef __bf16 bf16;
typedef __bf16 bf16x4 __attribute__((ext_vector_type(4)));
typedef __bf16 bf16x8 __attribute__((ext_vector_type(8)));
typedef float  f32x4  __attribute__((ext_vector_type(4)));

typedef __attribute__((address_space(1))) void gvoid_t;
typedef __attribute__((address_space(3))) void lvoid_t;

static __device__ __forceinline__ void gload16(const void* g, void* l) {
  // async global->LDS, 16B per lane; LDS dest wave-uniform base (HW adds lane*16)
  __builtin_amdgcn_global_load_lds((gvoid_t*)g, (lvoid_t*)l, 16, 0, 0);
}

static __device__ __forceinline__ float fexp2(float x) {
  return __builtin_amdgcn_exp2f(x);   // v_exp_f32: 2^x
}

static __device__ __forceinline__ unsigned pack2bf(float lo, float hi) {
  unsigned short l = __builtin_bit_cast(unsigned short, (bf16)lo);
  unsigned short h = __builtin_bit_cast(unsigned short, (bf16)hi);
  return ((unsigned)h << 16) | (unsigned)l;
}

// ---------------------------------------------------------------- converts
__global__ __launch_bounds__(256) void cvt_bf16(const float* __restrict__ in,
                                                bf16* __restrict__ out, int n8) {
  int i = blockIdx.x * 256 + threadIdx.x;
  if (i >= n8) return;
  const float4* p = (const float4*)(in + (size_t)i * 8);
  float4 v0 = p[0], v1 = p[1];
  bf16x8 o;
  o[0] = (bf16)v0.x; o[1] = (bf16)v0.y; o[2] = (bf16)v0.z; o[3] = (bf16)v0.w;
  o[4] = (bf16)v1.x; o[5] = (bf16)v1.y; o[6] = (bf16)v1.z; o[7] = (bf16)v1.w;
  *(bf16x8*)(out + (size_t)i * 8) = o;
}

// W [K][N] fp32 -> Wt [N][K] bf16 (32x32 LDS tiles)
__global__ __launch_bounds__(256) void tcvt(const float* __restrict__ W,
                                            bf16* __restrict__ Wt, int K, int N) {
  __shared__ float t[32][33];
  const int tid = threadIdx.x;
  const int r = tid >> 3, c4 = (tid & 7) * 4;
  const size_t grow = (size_t)(blockIdx.y * 32 + r);
  float4 v = *(const float4*)(W + grow * N + blockIdx.x * 32 + c4);
  t[r][c4 + 0] = v.x; t[r][c4 + 1] = v.y; t[r][c4 + 2] = v.z; t[r][c4 + 3] = v.w;
  __syncthreads();
  bf16x4 o = { (bf16)t[c4 + 0][r], (bf16)t[c4 + 1][r], (bf16)t[c4 + 2][r], (bf16)t[c4 + 3][r] };
  *(bf16x4*)(Wt + (size_t)(blockIdx.x * 32 + r) * K + blockIdx.y * 32 + c4) = o;
}

// ---------------------------------------------------------------- GEMM (NT)
// C[M][N] = A[M][K] * Bt[N][K]^T ; 128x128 tile, BK=64, 4 waves, m97 structure
template <typename OutT>
__global__ __launch_bounds__(256) void gemm_bt(const bf16* __restrict__ A,
                                               const bf16* __restrict__ Bt,
                                               OutT* __restrict__ C,
                                               int N, int K) {
  __shared__ bf16 As[128 * 64];
  __shared__ bf16 Bs[128 * 64];
  const int tid = threadIdx.x;
  const int wid = tid >> 6, lane = tid & 63;
  const int g = lane >> 4, c = lane & 15;
  const int brow = blockIdx.y * 128, bcol = blockIdx.x * 128;
  const int wr = (wid >> 1) * 64, wc = (wid & 1) * 64;
  f32x4 acc[4][4] = {};

  for (int k0 = 0; k0 < K; k0 += 64) {
#pragma unroll
    for (int i = 0; i < 4; ++i) {
      const int off = i * 4096 + tid * 16;       // byte offset in 16KB tile
      const int row = off >> 7, colb = off & 127;
      gload16((const char*)A + ((size_t)(brow + row) * K + k0) * 2 + colb,
              (char*)As + i * 4096 + wid * 1024);
      gload16((const char*)Bt + ((size_t)(bcol + row) * K + k0) * 2 + colb,
              (char*)Bs + i * 4096 + wid * 1024);
    }
    __syncthreads();
#pragma unroll
    for (int ks = 0; ks < 2; ++ks) {
      bf16x8 af[4], bfr[4];
#pragma unroll
      for (int t = 0; t < 4; ++t) {
        af[t]  = *(const bf16x8*)(As + (wr + t * 16 + c) * 64 + ks * 32 + g * 8);
        bfr[t] = *(const bf16x8*)(Bs + (wc + t * 16 + c) * 64 + ks * 32 + g * 8);
      }
#pragma unroll
      for (int mt = 0; mt < 4; ++mt)
#pragma unroll
        for (int nt = 0; nt < 4; ++nt)
          acc[mt][nt] = __builtin_amdgcn_mfma_f32_16x16x32_bf16(af[mt], bfr[nt], acc[mt][nt], 0, 0, 0);
    }
    __syncthreads();
  }
#pragma unroll
  for (int mt = 0; mt < 4; ++mt)
#pragma unroll
    for (int nt = 0; nt < 4; ++nt)
#pragma unroll
      for (int r = 0; r < 4; ++r) {
        const int row = brow + wr + mt * 16 + 4 * g + r;
        const int col = bcol + wc + nt * 16 + c;
        C[(size_t)row * N + col] = (OutT)acc[mt][nt][r];
      }
}

// ------------------------------------------- RMSNorm + RoPE epilogues
// q in-place: [4096][24*128], pos = row % 2048
__global__ __launch_bounds__(256) void nrope_q(bf16* __restrict__ q,
                                               const float* __restrict__ gw,
                                               const float* __restrict__ cache) {
  const int w = blockIdx.x * 4 + (threadIdx.x >> 6);
  const int lane = threadIdx.x & 63;
  const int row = w / 24, head = w % 24;
  const int pos = row & 2047;
  bf16* p = q + (size_t)row * 3072 + head * 128;
  float x1 = (float)p[lane], x2 = (float)p[64 + lane];
  float ss = x1 * x1 + x2 * x2;
#pragma unroll
  for (int m = 32; m; m >>= 1) ss += __shfl_xor(ss, m);
  const float inv = rsqrtf(ss * (1.0f / 128.0f) + 1e-6f);
  const float xn1 = x1 * inv * gw[lane], xn2 = x2 * inv * gw[64 + lane];
  const float cs = cache[pos * 128 + lane], sn = cache[pos * 128 + 64 + lane];
  p[lane]      = (bf16)(xn1 * cs - xn2 * sn);
  p[64 + lane] = (bf16)(xn2 * cs + xn1 * sn);
}

// k/tk: src [B*S][8*128] -> kf [b*8+hkv][2560][128] SWIZZLED (d' = d ^ ((key&7)<<3))
__global__ __launch_bounds__(256) void nrope_k(const bf16* __restrict__ src,
                                               bf16* __restrict__ kf,
                                               const float* __restrict__ gw,
                                               const float* __restrict__ cache,
                                               int S, int key_off) {
  const int w = blockIdx.x * 4 + (threadIdx.x >> 6);
  const int lane = threadIdx.x & 63;
  const int row = w >> 3, hkv = w & 7;
  const int b = row / S, s = row % S;
  const bf16* p = src + (size_t)row * 1024 + hkv * 128;
  float x1 = (float)p[lane], x2 = (float)p[64 + lane];
  float ss = x1 * x1 + x2 * x2;
#pragma unroll
  for (int m = 32; m; m >>= 1) ss += __shfl_xor(ss, m);
  const float inv = rsqrtf(ss * (1.0f / 128.0f) + 1e-6f);
  const float xn1 = x1 * inv * gw[lane], xn2 = x2 * inv * gw[64 + lane];
  const float cs = cache[s * 128 + lane], sn = cache[s * 128 + 64 + lane];
  bf16* o = kf + ((size_t)(b * 8 + hkv) * 2560 + key_off + s) * 128;
  const int dsw = lane ^ ((s & 7) << 3);     // key_off is 0 mod 8, so key&7 == s&7
  o[dsw]      = (bf16)(xn1 * cs - xn2 * sn);
  o[64 + dsw] = (bf16)(xn2 * cs + xn1 * sn);
}

// v/tv: src [B*S][8*128] -> vt [b*8+hkv][128][2560] (transposed), 32x32 LDS tiles
__global__ __launch_bounds__(256) void transpose_v(const bf16* __restrict__ src,
                                                   bf16* __restrict__ vtp,
                                                   int S, int key_off) {
  __shared__ bf16 t[32][33];
  const int tid = threadIdx.x;
  const int bh = blockIdx.z;       // b*8+hkv
  const int b = bh >> 3, hkv = bh & 7;
  const int s0 = blockIdx.x * 32, d0 = blockIdx.y * 32;
  const int r = tid >> 3, c4 = (tid & 7) * 4;
  bf16x4 v = *(const bf16x4*)(src + (size_t)(b * S + s0 + r) * 1024 + hkv * 128 + d0 + c4);
  t[r][c4 + 0] = v[0]; t[r][c4 + 1] = v[1]; t[r][c4 + 2] = v[2]; t[r][c4 + 3] = v[3];
  __syncthreads();
  bf16x4 o = { t[c4 + 0][r], t[c4 + 1][r], t[c4 + 2][r], t[c4 + 3][r] };
  *(bf16x4*)(vtp + ((size_t)bh * 128 + d0 + r) * 2560 + key_off + s0 + c4) = o;
}

// ---------------------------------------------------------------- attention
// 768 blocks, XCD-chunked; 128 q/block, 4 waves x 32 q; K LDS-staged (dbuf, swizzled)
__global__ __launch_bounds__(256) void attn_kernel(const bf16* __restrict__ qf,   // [4096][3072]
                                                   const bf16* __restrict__ kf,   // [16][2560][128] swz
                                                   const bf16* __restrict__ vtp,  // [16][128][2560]
                                                   bf16* __restrict__ attnb) {    // [4096][3072]
  __shared__ bf16 Ks[2][32 * 128];   // 2 x 8KB swizzled K tiles
  __shared__ bf16 osm[4][32 * 128];  // 32KB epilogue staging (swizzled)
  const int tid = threadIdx.x;
  const int wid = tid >> 6, lane = tid & 63;
  const int g = lane >> 4, c = lane & 15;
  // XCD-chunked remap: 96 consecutive blocks per XCD -> per-XCD K/V set = 2.6MB (L2-fit)
  const int bid0 = blockIdx.x + 16 * (blockIdx.y + 24 * (int)blockIdx.z);
  const int bid  = (bid0 & 7) * 96 + (bid0 >> 3);
  const int qb = bid & 15;
  const int h  = (bid >> 4) % 24;
  const int b  = bid / 384;
  const int q0 = qb * 128 + wid * 32;
  const int hkv = h / 3;
  const size_t kbase = (size_t)(b * 8 + hkv) * 2560 * 128;
  const size_t vbase = (size_t)(b * 8 + hkv) * 128 * 2560;

  bf16x8 qfrag[2][4];
#pragma unroll
  for (int qt = 0; qt < 2; ++qt) {
    const size_t qrow = (size_t)(b * 2048 + q0 + qt * 16 + c) * 3072 + h * 128;
#pragma unroll
    for (int kc = 0; kc < 4; ++kc)
      qfrag[qt][kc] = *(const bf16x8*)(qf + qrow + kc * 32 + g * 8);
  }

  f32x4 ot[2][8] = {};
  float mrun[2] = { -__builtin_inff(), -__builtin_inff() };
  float lsum[2] = { 0.f, 0.f };
  const float sc2 = 0.08838834764831845f * 1.4426950408889634f;  // 1/sqrt(128) * log2(e)

  // stage K tile: 8KB contiguous; per wave two 1KB chunks
  auto stageK = [&](int key0, int buf) {
    const char* gsrc = (const char*)kf + (kbase + (size_t)key0 * 128) * 2 + wid * 2048 + lane * 16;
    char* ldst = (char*)&Ks[buf][0] + wid * 2048;
    gload16(gsrc, ldst);
    gload16(gsrc + 1024, ldst + 1024);
  };

  stageK(0, 0);
  __syncthreads();

  for (int key0 = 0, it = 0; key0 < 2560; key0 += 32, ++it) {
    const int cur = it & 1;
    if (key0 + 32 < 2560) stageK(key0 + 32, cur ^ 1);

    // V loads issued early (consumed after softmax)
    bf16x8 vfrag[8];
#pragma unroll
    for (int dt = 0; dt < 8; ++dt)
      vfrag[dt] = *(const bf16x8*)(vtp + vbase + (size_t)(dt * 16 + c) * 2560 + key0 + g * 8);

    // QK^T from LDS (swizzled reads): S^T = mfma(K, Q)
    const char* Kb = (const char*)&Ks[cur][0];
    f32x4 s[2][2] = {};
    __builtin_amdgcn_s_setprio(1);
#pragma unroll
    for (int kc = 0; kc < 4; ++kc) {
      const int bsw = (kc * 64 + g * 16) ^ ((c & 7) << 4);
      bf16x8 a0 = *(const bf16x8*)(Kb + c * 256 + bsw);
      bf16x8 a1 = *(const bf16x8*)(Kb + (c + 16) * 256 + bsw);
#pragma unroll
      for (int qt = 0; qt < 2; ++qt) {
        s[qt][0] = __builtin_amdgcn_mfma_f32_16x16x32_bf16(a0, qfrag[qt][kc], s[qt][0], 0, 0, 0);
        s[qt][1] = __builtin_amdgcn_mfma_f32_16x16x32_bf16(a1, qfrag[qt][kc], s[qt][1], 0, 0, 0);
      }
    }
    __builtin_amdgcn_s_setprio(0);

#pragma unroll
    for (int qt = 0; qt < 2; ++qt) {
      float p0[4], p1[4];
      float tmax = -__builtin_inff();
#pragma unroll
      for (int r = 0; r < 4; ++r) {
        p0[r] = s[qt][0][r] * sc2;
        p1[r] = s[qt][1][r] * sc2;
        tmax = fmaxf(tmax, fmaxf(p0[r], p1[r]));
      }
      tmax = fmaxf(tmax, __shfl_xor(tmax, 16));
      tmax = fmaxf(tmax, __shfl_xor(tmax, 32));
      // defer-max (T13): skip O-rescale while tile max stays within +8 of running max
      const bool defer = __all(tmax <= mrun[qt] + 8.f);
      if (!defer) {
        const float mnew = fmaxf(mrun[qt], tmax);
        const float alpha = fexp2(mrun[qt] - mnew);
        lsum[qt] *= alpha;
#pragma unroll
        for (int dt = 0; dt < 8; ++dt)
#pragma unroll
          for (int r = 0; r < 4; ++r) ot[qt][dt][r] *= alpha;
        mrun[qt] = mnew;
      }
      const float m2 = mrun[qt];
      float psum = 0.f;
#pragma unroll
      for (int r = 0; r < 4; ++r) {
        p0[r] = fexp2(p0[r] - m2);
        p1[r] = fexp2(p1[r] - m2);
        psum += p0[r] + p1[r];
      }
      psum += __shfl_xor(psum, 16);
      psum += __shfl_xor(psum, 32);
      lsum[qt] += psum;
      // packed P redistribution: one u32 (p0,p1 as 2xbf16) per r, 8 bpermutes per qt
      const int srcA = 2 * (g & 1) * 16 + c;
      const bool t1 = (g >= 2);
      union { bf16x8 v; unsigned short us[8]; } pf;
#pragma unroll
      for (int r = 0; r < 4; ++r) {
        const unsigned pk = pack2bf(p0[r], p1[r]);
        const unsigned a  = __shfl(pk, srcA);
        const unsigned bb = __shfl(pk, srcA + 16);
        pf.us[r]     = (unsigned short)(t1 ? (a >> 16)  : (a & 0xffff));
        pf.us[4 + r] = (unsigned short)(t1 ? (bb >> 16) : (bb & 0xffff));
      }
      __builtin_amdgcn_s_setprio(1);
#pragma unroll
      for (int dt = 0; dt < 8; ++dt)
        ot[qt][dt] = __builtin_amdgcn_mfma_f32_16x16x32_bf16(vfrag[dt], pf.v, ot[qt][dt], 0, 0, 0);
      __builtin_amdgcn_s_setprio(0);
    }
    __syncthreads();
  }

  // O^T[d][q] -> LDS [q][d] (swizzled) -> coalesced global
#pragma unroll
  for (int qt = 0; qt < 2; ++qt) {
    const float inv = 1.0f / lsum[qt];
#pragma unroll
    for (int dt = 0; dt < 8; ++dt)
#pragma unroll
      for (int r = 0; r < 4; ++r) {
        const int q = qt * 16 + c;
        const int byteoff = ((dt * 16 + 4 * g + r) * 2) ^ ((q & 7) << 4);
        *(bf16*)((char*)&osm[wid][0] + q * 256 + byteoff) = (bf16)(ot[qt][dt][r] * inv);
      }
  }
#pragma unroll
  for (int it = 0; it < 8; ++it) {
    const int off = it * 1024 + lane * 16;    // byte in 8KB tile
    const int qrow = off >> 8, colb = off & 255;
    bf16x8 v = *(const bf16x8*)((const char*)&osm[wid][0] + qrow * 256 + (colb ^ ((qrow & 7) << 4)));
    *(bf16x8*)((char*)attnb + ((size_t)(b * 2048 + q0 + qrow) * 3072 + h * 128) * 2 + colb) = v;
  }
}

// ---------------------------------------------------------------- launcher
extern "C" void kernel_launch(void* const* d_in, const int* in_sizes, int n_in,
                              void* d_out, int out_size, void* d_ws, size_t ws_size,
                              hipStream_t stream) {
  const float* hs     = (const float*)d_in[0];
  const float* ehs    = (const float*)d_in[1];
  const float* Wq     = (const float*)d_in[2];
  const float* Wk     = (const float*)d_in[3];
  const float* Wv     = (const float*)d_in[4];
  const float* Wak    = (const float*)d_in[5];
  const float* Wav    = (const float*)d_in[6];
  const float* Wo     = (const float*)d_in[7];
  const float* gq     = (const float*)d_in[8];
  const float* gk     = (const float*)d_in[9];
  const float* gak    = (const float*)d_in[10];
  const float* icache = (const float*)d_in[11];
  const float* tcache = (const float*)d_in[12];

  char* ws = (char*)d_ws;
  bf16* hsb   = (bf16*)(ws + 0);            // 25.2MB, reused as attnb after q/k/v GEMMs
  bf16* ehsb  = (bf16*)(ws + 25165824);     // 6.3MB
  bf16* Wqt   = (bf16*)(ws + 31457280);     // 18.9MB
  bf16* Wkt   = (bf16*)(ws + 50331648);     // 6.3MB  (region Wkt..Wavt reused as qraw)
  bf16* Wvt   = (bf16*)(ws + 56623104);     // 6.3MB
  bf16* Wakt  = (bf16*)(ws + 62914560);     // 6.3MB
  bf16* Wavt  = (bf16*)(ws + 69206016);     // 6.3MB
  bf16* Wot   = (bf16*)(ws + 75497472);     // 18.9MB
  bf16* kraw  = (bf16*)(ws + 94371840);     // 8.4MB
  bf16* vraw  = (bf16*)(ws + 102760448);    // 8.4MB
  bf16* tkraw = (bf16*)(ws + 111149056);    // 2.1MB
  bf16* tvraw = (bf16*)(ws + 113246208);    // 2.1MB
  bf16* kf    = (bf16*)(ws + 115343360);    // 10.5MB joint K [16][2560][128] (swizzled)
  bf16* vt    = (bf16*)(ws + 125829120);    // 10.5MB joint V^T [16][128][2560]
  bf16* qraw  = (bf16*)(ws + 50331648);     // aliases Wkt..Wavt (dead by then)
  bf16* attnb = hsb;                        // aliases hsb (dead after q/k/v GEMMs)

  cvt_bf16<<<6144, 256, 0, stream>>>(hs, hsb, 1572864);
  cvt_bf16<<<1536, 256, 0, stream>>>(ehs, ehsb, 393216);
  tcvt<<<dim3(96, 96), 256, 0, stream>>>(Wq,  Wqt,  3072, 3072);
  tcvt<<<dim3(32, 96), 256, 0, stream>>>(Wk,  Wkt,  3072, 1024);
  tcvt<<<dim3(32, 96), 256, 0, stream>>>(Wv,  Wvt,  3072, 1024);
  tcvt<<<dim3(32, 96), 256, 0, stream>>>(Wak, Wakt, 3072, 1024);
  tcvt<<<dim3(32, 96), 256, 0, stream>>>(Wav, Wavt, 3072, 1024);
  tcvt<<<dim3(96, 96), 256, 0, stream>>>(Wo,  Wot,  3072, 3072);

  gemm_bt<bf16><<<dim3(8, 32), 256, 0, stream>>>(hsb,  Wkt,  kraw,  1024, 3072);
  gemm_bt<bf16><<<dim3(8, 32), 256, 0, stream>>>(hsb,  Wvt,  vraw,  1024, 3072);
  gemm_bt<bf16><<<dim3(8, 8),  256, 0, stream>>>(ehsb, Wakt, tkraw, 1024, 3072);
  gemm_bt<bf16><<<dim3(8, 8),  256, 0, stream>>>(ehsb, Wavt, tvraw, 1024, 3072);
  gemm_bt<bf16><<<dim3(24, 32), 256, 0, stream>>>(hsb, Wqt,  qraw,  3072, 3072);

  nrope_q<<<24576, 256, 0, stream>>>(qraw, gq, icache);
  nrope_k<<<8192, 256, 0, stream>>>(kraw,  kf, gk,  icache, 2048, 0);
  nrope_k<<<2048, 256, 0, stream>>>(tkraw, kf, gak, tcache, 512,  2048);
  transpose_v<<<dim3(64, 4, 16), 256, 0, stream>>>(vraw,  vt, 2048, 0);
  transpose_v<<<dim3(16, 4, 16), 256, 0, stream>>>(tvraw, vt, 512,  2048);

  attn_kernel<<<dim3(16, 24, 2), 256, 0, stream>>>(qraw, kf, vt, attnb);

  gemm_bt<float><<<dim3(24, 32), 256, 0, stream>>>(attnb, Wot, (float*)d_out, 3072, 3072);
}

// Round 5
// 961.923 us; speedup vs baseline: 1.1649x; 1.0369x over previous
//
#include <hip/hip_runtime.h>
#include <hip/hip_bf16.h>
#include <math.h>

typedef __bf16 bf16;
typedef __bf16 bf16x4 __attribute__((ext_vector_type(4)));
typedef __bf16 bf16x8 __attribute__((ext_vector_type(8)));
typedef float  f32x4  __attribute__((ext_vector_type(4)));

typedef __attribute__((address_space(1))) void gvoid_t;
typedef __attribute__((address_space(3))) void lvoid_t;

static __device__ __forceinline__ void gload16(const void* g, void* l) {
  // async global->LDS, 16B per lane; LDS dest wave-uniform base (HW adds lane*16)
  __builtin_amdgcn_global_load_lds((gvoid_t*)g, (lvoid_t*)l, 16, 0, 0);
}

static __device__ __forceinline__ float fexp2(float x) {
  return __builtin_amdgcn_exp2f(x);   // v_exp_f32: 2^x
}

static __device__ __forceinline__ unsigned pack2bf(float lo, float hi) {
  unsigned short l = __builtin_bit_cast(unsigned short, (bf16)lo);
  unsigned short h = __builtin_bit_cast(unsigned short, (bf16)hi);
  return ((unsigned)h << 16) | (unsigned)l;
}

// ---------------------------------------------------------------- converts
__global__ __launch_bounds__(256) void cvt_bf16(const float* __restrict__ in,
                                                bf16* __restrict__ out, int n8) {
  int i = blockIdx.x * 256 + threadIdx.x;
  if (i >= n8) return;
  const float4* p = (const float4*)(in + (size_t)i * 8);
  float4 v0 = p[0], v1 = p[1];
  bf16x8 o;
  o[0] = (bf16)v0.x; o[1] = (bf16)v0.y; o[2] = (bf16)v0.z; o[3] = (bf16)v0.w;
  o[4] = (bf16)v1.x; o[5] = (bf16)v1.y; o[6] = (bf16)v1.z; o[7] = (bf16)v1.w;
  *(bf16x8*)(out + (size_t)i * 8) = o;
}

// W [K][N] fp32 -> Wt [N][K] bf16 (32x32 LDS tiles)
__global__ __launch_bounds__(256) void tcvt(const float* __restrict__ W,
                                            bf16* __restrict__ Wt, int K, int N) {
  __shared__ float t[32][33];
  const int tid = threadIdx.x;
  const int r = tid >> 3, c4 = (tid & 7) * 4;
  const size_t grow = (size_t)(blockIdx.y * 32 + r);
  float4 v = *(const float4*)(W + grow * N + blockIdx.x * 32 + c4);
  t[r][c4 + 0] = v.x; t[r][c4 + 1] = v.y; t[r][c4 + 2] = v.z; t[r][c4 + 3] = v.w;
  __syncthreads();
  bf16x4 o = { (bf16)t[c4 + 0][r], (bf16)t[c4 + 1][r], (bf16)t[c4 + 2][r], (bf16)t[c4 + 3][r] };
  *(bf16x4*)(Wt + (size_t)(blockIdx.x * 32 + r) * K + blockIdx.y * 32 + c4) = o;
}

// ---------------------------------------------------------------- GEMM (NT)
// C[M][N] = A[M][K] * Bt[N][K]^T ; 128x128 tile, BK=64, 4 waves, m97 structure
template <typename OutT>
__global__ __launch_bounds__(256) void gemm_bt(const bf16* __restrict__ A,
                                               const bf16* __restrict__ Bt,
                                               OutT* __restrict__ C,
                                               int N, int K) {
  __shared__ bf16 As[128 * 64];
  __shared__ bf16 Bs[128 * 64];
  const int tid = threadIdx.x;
  const int wid = tid >> 6, lane = tid & 63;
  const int g = lane >> 4, c = lane & 15;
  const int brow = blockIdx.y * 128, bcol = blockIdx.x * 128;
  const int wr = (wid >> 1) * 64, wc = (wid & 1) * 64;
  f32x4 acc[4][4] = {};

  for (int k0 = 0; k0 < K; k0 += 64) {
#pragma unroll
    for (int i = 0; i < 4; ++i) {
      const int off = i * 4096 + tid * 16;       // byte offset in 16KB tile
      const int row = off >> 7, colb = off & 127;
      gload16((const char*)A + ((size_t)(brow + row) * K + k0) * 2 + colb,
              (char*)As + i * 4096 + wid * 1024);
      gload16((const char*)Bt + ((size_t)(bcol + row) * K + k0) * 2 + colb,
              (char*)Bs + i * 4096 + wid * 1024);
    }
    __syncthreads();
#pragma unroll
    for (int ks = 0; ks < 2; ++ks) {
      bf16x8 af[4], bfr[4];
#pragma unroll
      for (int t = 0; t < 4; ++t) {
        af[t]  = *(const bf16x8*)(As + (wr + t * 16 + c) * 64 + ks * 32 + g * 8);
        bfr[t] = *(const bf16x8*)(Bs + (wc + t * 16 + c) * 64 + ks * 32 + g * 8);
      }
#pragma unroll
      for (int mt = 0; mt < 4; ++mt)
#pragma unroll
        for (int nt = 0; nt < 4; ++nt)
          acc[mt][nt] = __builtin_amdgcn_mfma_f32_16x16x32_bf16(af[mt], bfr[nt], acc[mt][nt], 0, 0, 0);
    }
    __syncthreads();
  }
#pragma unroll
  for (int mt = 0; mt < 4; ++mt)
#pragma unroll
    for (int nt = 0; nt < 4; ++nt)
#pragma unroll
      for (int r = 0; r < 4; ++r) {
        const int row = brow + wr + mt * 16 + 4 * g + r;
        const int col = bcol + wc + nt * 16 + c;
        C[(size_t)row * N + col] = (OutT)acc[mt][nt][r];
      }
}

// ------------------------------------------- RMSNorm + RoPE epilogues
// q in-place within qkvC: [4096][stride], pos = row % 2048
__global__ __launch_bounds__(256) void nrope_q(bf16* __restrict__ q, int stride,
                                               const float* __restrict__ gw,
                                               const float* __restrict__ cache) {
  const int w = blockIdx.x * 4 + (threadIdx.x >> 6);
  const int lane = threadIdx.x & 63;
  const int row = w / 24, head = w % 24;
  const int pos = row & 2047;
  bf16* p = q + (size_t)row * stride + head * 128;
  float x1 = (float)p[lane], x2 = (float)p[64 + lane];
  float ss = x1 * x1 + x2 * x2;
#pragma unroll
  for (int m = 32; m; m >>= 1) ss += __shfl_xor(ss, m);
  const float inv = rsqrtf(ss * (1.0f / 128.0f) + 1e-6f);
  const float xn1 = x1 * inv * gw[lane], xn2 = x2 * inv * gw[64 + lane];
  const float cs = cache[pos * 128 + lane], sn = cache[pos * 128 + 64 + lane];
  p[lane]      = (bf16)(xn1 * cs - xn2 * sn);
  p[64 + lane] = (bf16)(xn2 * cs + xn1 * sn);
}

// k/tk: src [B*S][stride] (+base col) -> kf [b*8+hkv][2560][128] SWIZZLED (d' = d ^ ((key&7)<<3))
__global__ __launch_bounds__(256) void nrope_k(const bf16* __restrict__ src, int stride, int base,
                                               bf16* __restrict__ kf,
                                               const float* __restrict__ gw,
                                               const float* __restrict__ cache,
                                               int S, int key_off) {
  const int w = blockIdx.x * 4 + (threadIdx.x >> 6);
  const int lane = threadIdx.x & 63;
  const int row = w >> 3, hkv = w & 7;
  const int b = row / S, s = row % S;
  const bf16* p = src + (size_t)row * stride + base + hkv * 128;
  float x1 = (float)p[lane], x2 = (float)p[64 + lane];
  float ss = x1 * x1 + x2 * x2;
#pragma unroll
  for (int m = 32; m; m >>= 1) ss += __shfl_xor(ss, m);
  const float inv = rsqrtf(ss * (1.0f / 128.0f) + 1e-6f);
  const float xn1 = x1 * inv * gw[lane], xn2 = x2 * inv * gw[64 + lane];
  const float cs = cache[s * 128 + lane], sn = cache[s * 128 + 64 + lane];
  bf16* o = kf + ((size_t)(b * 8 + hkv) * 2560 + key_off + s) * 128;
  const int dsw = lane ^ ((s & 7) << 3);     // key_off is 0 mod 8, so key&7 == s&7
  o[dsw]      = (bf16)(xn1 * cs - xn2 * sn);
  o[64 + dsw] = (bf16)(xn2 * cs + xn1 * sn);
}

// v/tv: src [B*S][stride] (+base col) -> vt [b*8+hkv][128][2560] (transposed)
__global__ __launch_bounds__(256) void transpose_v(const bf16* __restrict__ src, int stride, int base,
                                                   bf16* __restrict__ vtp,
                                                   int S, int key_off) {
  __shared__ bf16 t[32][33];
  const int tid = threadIdx.x;
  const int bh = blockIdx.z;       // b*8+hkv
  const int b = bh >> 3, hkv = bh & 7;
  const int s0 = blockIdx.x * 32, d0 = blockIdx.y * 32;
  const int r = tid >> 3, c4 = (tid & 7) * 4;
  bf16x4 v = *(const bf16x4*)(src + (size_t)(b * S + s0 + r) * stride + base + hkv * 128 + d0 + c4);
  t[r][c4 + 0] = v[0]; t[r][c4 + 1] = v[1]; t[r][c4 + 2] = v[2]; t[r][c4 + 3] = v[3];
  __syncthreads();
  bf16x4 o = { t[c4 + 0][r], t[c4 + 1][r], t[c4 + 2][r], t[c4 + 3][r] };
  *(bf16x4*)(vtp + ((size_t)bh * 128 + d0 + r) * 2560 + key_off + s0 + c4) = o;
}

// ---------------------------------------------------------------- attention
// 1536 blocks XCD-chunked; 64 q/block, 4 waves x 16 q; K LDS-staged (dbuf, swizzled), 16KB LDS
__global__ __launch_bounds__(256, 4) void attn_kernel(const bf16* __restrict__ qf,   // [4096][5120] (q cols)
                                                      const bf16* __restrict__ kf,   // [16][2560][128] swz
                                                      const bf16* __restrict__ vtp,  // [16][128][2560]
                                                      bf16* __restrict__ attnb) {    // [4096][3072]
  __shared__ bf16 Ks[2][32 * 128];   // 2 x 8KB swizzled K tiles; reused as epilogue staging
  const int tid = threadIdx.x;
  const int wid = tid >> 6, lane = tid & 63;
  const int g = lane >> 4, c = lane & 15;
  // XCD-chunked remap: 192 consecutive blocks per XCD (6 heads -> 2 hkv, L2-fit K/V)
  const int bid0 = blockIdx.x;
  const int bid  = (bid0 & 7) * 192 + (bid0 >> 3);
  const int qb = bid & 31;
  const int hb = bid >> 5;
  const int h  = hb % 24;
  const int b  = hb / 24;
  const int q0 = qb * 64 + wid * 16;     // this wave's 16 q rows
  const int hkv = h / 3;
  const size_t kbase = (size_t)(b * 8 + hkv) * 2560 * 128;
  const size_t vbase = (size_t)(b * 8 + hkv) * 128 * 2560;

  bf16x8 qfrag[4];
  {
    const size_t qrow = (size_t)(b * 2048 + q0 + c) * 5120 + h * 128;
#pragma unroll
    for (int kc = 0; kc < 4; ++kc)
      qfrag[kc] = *(const bf16x8*)(qf + qrow + kc * 32 + g * 8);
  }

  f32x4 ot[8] = {};
  float mrun = -__builtin_inff();
  float lsum = 0.f;                      // per-lane partial (reduced across g at the end)
  const float sc2 = 0.08838834764831845f * 1.4426950408889634f;  // 1/sqrt(128) * log2(e)

  // stage K tile: 8KB; per wave 2KB (2 x 1KB gload16)
  auto stageK = [&](int key0, int buf) {
    const char* gsrc = (const char*)kf + (kbase + (size_t)key0 * 128) * 2 + wid * 2048 + lane * 16;
    char* ldst = (char*)&Ks[buf][0] + wid * 2048;
    gload16(gsrc, ldst);
    gload16(gsrc + 1024, ldst + 1024);
  };

  stageK(0, 0);
  __syncthreads();

  for (int key0 = 0, it = 0; key0 < 2560; key0 += 32, ++it) {
    const int cur = it & 1;
    if (key0 + 32 < 2560) stageK(key0 + 32, cur ^ 1);

    // V loads issued early (consumed after softmax)
    bf16x8 vfrag[8];
#pragma unroll
    for (int dt = 0; dt < 8; ++dt)
      vfrag[dt] = *(const bf16x8*)(vtp + vbase + (size_t)(dt * 16 + c) * 2560 + key0 + g * 8);

    // QK^T from LDS (swizzled reads): S^T = mfma(K, Q); lane holds S[q=c][4g+r | 16+4g+r]
    const char* Kb = (const char*)&Ks[cur][0];
    f32x4 s0 = {}, s1 = {};
    __builtin_amdgcn_s_setprio(1);
#pragma unroll
    for (int kc = 0; kc < 4; ++kc) {
      const int bsw = (kc * 64 + g * 16) ^ ((c & 7) << 4);
      bf16x8 a0 = *(const bf16x8*)(Kb + c * 256 + bsw);
      bf16x8 a1 = *(const bf16x8*)(Kb + (c + 16) * 256 + bsw);
      s0 = __builtin_amdgcn_mfma_f32_16x16x32_bf16(a0, qfrag[kc], s0, 0, 0, 0);
      s1 = __builtin_amdgcn_mfma_f32_16x16x32_bf16(a1, qfrag[kc], s1, 0, 0, 0);
    }
    __builtin_amdgcn_s_setprio(0);

    float p0[4], p1[4];
    float tmax = -__builtin_inff();
#pragma unroll
    for (int r = 0; r < 4; ++r) {
      p0[r] = s0[r] * sc2;
      p1[r] = s1[r] * sc2;
      tmax = fmaxf(tmax, fmaxf(p0[r], p1[r]));
    }
    // defer-max (T13): per-lane check, no cross-lane reduce on the common path
    if (!__all(tmax <= mrun + 8.f)) {
      tmax = fmaxf(tmax, __shfl_xor(tmax, 16));
      tmax = fmaxf(tmax, __shfl_xor(tmax, 32));
      const float mnew = fmaxf(mrun, tmax);
      const float alpha = fexp2(mrun - mnew);
      lsum *= alpha;
#pragma unroll
      for (int dt = 0; dt < 8; ++dt)
#pragma unroll
        for (int r = 0; r < 4; ++r) ot[dt][r] *= alpha;
      mrun = mnew;
    }
#pragma unroll
    for (int r = 0; r < 4; ++r) {
      p0[r] = fexp2(p0[r] - mrun);
      p1[r] = fexp2(p1[r] - mrun);
      lsum += p0[r] + p1[r];             // per-lane partial; g-reduce deferred to epilogue
    }
    // packed P redistribution: lane needs P[q=c][key = 8g+j]; 8 parallel bpermutes
    const int srcA = 2 * (g & 1) * 16 + c;
    const bool t1 = (g >= 2);
    union { bf16x8 v; unsigned short us[8]; } pf;
#pragma unroll
    for (int r = 0; r < 4; ++r) {
      const unsigned pk = pack2bf(p0[r], p1[r]);
      const unsigned a  = __shfl(pk, srcA);
      const unsigned bb = __shfl(pk, srcA + 16);
      pf.us[r]     = (unsigned short)(t1 ? (a >> 16)  : (a & 0xffff));
      pf.us[4 + r] = (unsigned short)(t1 ? (bb >> 16) : (bb & 0xffff));
    }
    __builtin_amdgcn_s_setprio(1);
#pragma unroll
    for (int dt = 0; dt < 8; ++dt)
      ot[dt] = __builtin_amdgcn_mfma_f32_16x16x32_bf16(vfrag[dt], pf.v, ot[dt], 0, 0, 0);
    __builtin_amdgcn_s_setprio(0);
    __syncthreads();
  }

  // finalize lsum across the 4 g-lanes (q = c fixed)
  lsum += __shfl_xor(lsum, 16);
  lsum += __shfl_xor(lsum, 32);
  const float inv = 1.0f / lsum;

  // O^T[d][q] -> per-wave 4KB LDS tile (aliases Ks, dead now) -> coalesced global
  char* osm = (char*)&Ks[0][0] + wid * 4096;    // 16 rows x 256B, swizzled
#pragma unroll
  for (int dt = 0; dt < 8; ++dt) {
    uint2 w2;
    w2.x = pack2bf(ot[dt][0] * inv, ot[dt][1] * inv);
    w2.y = pack2bf(ot[dt][2] * inv, ot[dt][3] * inv);
    *(uint2*)(osm + c * 256 + ((dt * 32 + 8 * g) ^ ((c & 7) << 4))) = w2;
  }
  __syncthreads();
#pragma unroll
  for (int it = 0; it < 4; ++it) {
    const int off = it * 1024 + lane * 16;    // byte in 4KB tile
    const int qrow = off >> 8, colb = off & 255;
    bf16x8 v = *(const bf16x8*)(osm + qrow * 256 + (colb ^ ((qrow & 7) << 4)));
    *(bf16x8*)((char*)attnb + ((size_t)(b * 2048 + q0 + qrow) * 3072 + h * 128) * 2 + colb) = v;
  }
}

// ---------------------------------------------------------------- launcher
extern "C" void kernel_launch(void* const* d_in, const int* in_sizes, int n_in,
                              void* d_out, int out_size, void* d_ws, size_t ws_size,
                              hipStream_t stream) {
  const float* hs     = (const float*)d_in[0];
  const float* ehs    = (const float*)d_in[1];
  const float* Wq     = (const float*)d_in[2];
  const float* Wk     = (const float*)d_in[3];
  const float* Wv     = (const float*)d_in[4];
  const float* Wak    = (const float*)d_in[5];
  const float* Wav    = (const float*)d_in[6];
  const float* Wo     = (const float*)d_in[7];
  const float* gq     = (const float*)d_in[8];
  const float* gk     = (const float*)d_in[9];
  const float* gak    = (const float*)d_in[10];
  const float* icache = (const float*)d_in[11];
  const float* tcache = (const float*)d_in[12];

  char* ws = (char*)d_ws;
  bf16* hsb    = (bf16*)(ws + 0);            // 25.2MB; reused as attnb after QKV GEMM
  bf16* Wcomb  = (bf16*)(ws + 25165824);     // [5120][3072] 31.5MB (Wq|Wk|Wv)^T; reused for Wot
  bf16* ehsb   = (bf16*)(ws + 56623104);     // 6.3MB; (ehsb+Wacomb region reused as vt)
  bf16* Wacomb = (bf16*)(ws + 62914560);     // [2048][3072] 12.6MB (Wak|Wav)^T
  bf16* qkvC   = (bf16*)(ws + 75497472);     // [4096][5120] 41.9MB (q|k|v)
  bf16* tC     = (bf16*)(ws + 117440512);    // [1024][2048] 4.2MB (tk|tv)
  bf16* kf     = (bf16*)(ws + 121634816);    // 10.5MB joint K [16][2560][128] (swizzled)
  bf16* Wot    = (bf16*)(ws + 25165824);     // 18.9MB, aliases Wcomb (dead after QKV GEMM)
  bf16* vt     = (bf16*)(ws + 56623104);     // 10.5MB joint V^T, aliases ehsb+Wacomb (dead after tGEMM)
  bf16* attnb  = hsb;                        // aliases hsb (dead after QKV GEMM)
  // max ws offset: 132,120,576 bytes

  cvt_bf16<<<6144, 256, 0, stream>>>(hs, hsb, 1572864);
  cvt_bf16<<<1536, 256, 0, stream>>>(ehs, ehsb, 393216);
  tcvt<<<dim3(96, 96), 256, 0, stream>>>(Wq,  Wcomb,                3072, 3072);
  tcvt<<<dim3(32, 96), 256, 0, stream>>>(Wk,  Wcomb + 3072 * 3072,  3072, 1024);
  tcvt<<<dim3(32, 96), 256, 0, stream>>>(Wv,  Wcomb + 4096 * 3072,  3072, 1024);
  tcvt<<<dim3(32, 96), 256, 0, stream>>>(Wak, Wacomb,               3072, 1024);
  tcvt<<<dim3(32, 96), 256, 0, stream>>>(Wav, Wacomb + 1024 * 3072, 3072, 1024);

  // fused QKV GEMM: [4096][3072] x [5120][3072]^T -> [4096][5120]
  gemm_bt<bf16><<<dim3(40, 32), 256, 0, stream>>>(hsb,  Wcomb,  qkvC, 5120, 3072);
  // fused tK/tV GEMM: [1024][3072] x [2048][3072]^T -> [1024][2048]
  gemm_bt<bf16><<<dim3(16, 8),  256, 0, stream>>>(ehsb, Wacomb, tC,   2048, 3072);

  // Wo transpose-convert AFTER QKV GEMM (reuses Wcomb region)
  tcvt<<<dim3(96, 96), 256, 0, stream>>>(Wo, Wot, 3072, 3072);

  nrope_q<<<24576, 256, 0, stream>>>(qkvC, 5120, gq, icache);
  nrope_k<<<8192, 256, 0, stream>>>(qkvC, 5120, 3072, kf, gk,  icache, 2048, 0);
  nrope_k<<<2048, 256, 0, stream>>>(tC,   2048, 0,    kf, gak, tcache, 512,  2048);
  transpose_v<<<dim3(64, 4, 16), 256, 0, stream>>>(qkvC, 5120, 4096, vt, 2048, 0);
  transpose_v<<<dim3(16, 4, 16), 256, 0, stream>>>(tC,   2048, 1024, vt, 512,  2048);

  attn_kernel<<<1536, 256, 0, stream>>>(qkvC, kf, vt, attnb);

  gemm_bt<float><<<dim3(24, 32), 256, 0, stream>>>(attnb, Wot, (float*)d_out, 3072, 3072);
}

// Round 6
// 926.575 us; speedup vs baseline: 1.2093x; 1.0381x over previous
//
#include <hip/hip_runtime.h>
#include <hip/hip_bf16.h>
#include <math.h>

typedef __bf16 bf16;
typedef __bf16 bf16x4 __attribute__((ext_vector_type(4)));
typedef __bf16 bf16x8 __attribute__((ext_vector_type(8)));
typedef float  f32x4  __attribute__((ext_vector_type(4)));

typedef __attribute__((address_space(1))) void gvoid_t;
typedef __attribute__((address_space(3))) void lvoid_t;

static __device__ __forceinline__ void gload16(const void* g, void* l) {
  // async global->LDS, 16B per lane; LDS dest wave-uniform base (HW adds lane*16)
  __builtin_amdgcn_global_load_lds((gvoid_t*)g, (lvoid_t*)l, 16, 0, 0);
}

static __device__ __forceinline__ float fexp2(float x) {
  return __builtin_amdgcn_exp2f(x);   // v_exp_f32: 2^x
}

static __device__ __forceinline__ unsigned pack2bf(float lo, float hi) {
  unsigned short l = __builtin_bit_cast(unsigned short, (bf16)lo);
  unsigned short h = __builtin_bit_cast(unsigned short, (bf16)hi);
  return ((unsigned)h << 16) | (unsigned)l;
}

// ---------------------------------------------------------------- converts
__global__ __launch_bounds__(256) void cvt_bf16(const float* __restrict__ in,
                                                bf16* __restrict__ out, int n8) {
  int i = blockIdx.x * 256 + threadIdx.x;
  if (i >= n8) return;
  const float4* p = (const float4*)(in + (size_t)i * 8);
  float4 v0 = p[0], v1 = p[1];
  bf16x8 o;
  o[0] = (bf16)v0.x; o[1] = (bf16)v0.y; o[2] = (bf16)v0.z; o[3] = (bf16)v0.w;
  o[4] = (bf16)v1.x; o[5] = (bf16)v1.y; o[6] = (bf16)v1.z; o[7] = (bf16)v1.w;
  *(bf16x8*)(out + (size_t)i * 8) = o;
}

// W [K][N] fp32 -> Wt [N][K] bf16 (32x32 LDS tiles)
__global__ __launch_bounds__(256) void tcvt(const float* __restrict__ W,
                                            bf16* __restrict__ Wt, int K, int N) {
  __shared__ float t[32][33];
  const int tid = threadIdx.x;
  const int r = tid >> 3, c4 = (tid & 7) * 4;
  const size_t grow = (size_t)(blockIdx.y * 32 + r);
  float4 v = *(const float4*)(W + grow * N + blockIdx.x * 32 + c4);
  t[r][c4 + 0] = v.x; t[r][c4 + 1] = v.y; t[r][c4 + 2] = v.z; t[r][c4 + 3] = v.w;
  __syncthreads();
  bf16x4 o = { (bf16)t[c4 + 0][r], (bf16)t[c4 + 1][r], (bf16)t[c4 + 2][r], (bf16)t[c4 + 3][r] };
  *(bf16x4*)(Wt + (size_t)(blockIdx.x * 32 + r) * K + blockIdx.y * 32 + c4) = o;
}

// ---------------------------------------------------------------- GEMM (NT)
// C[M][N] = A[M][K] * Bt[N][K]^T ; 128x128 tile, BK=64, 4 waves, m97 structure
template <typename OutT>
__global__ __launch_bounds__(256) void gemm_bt(const bf16* __restrict__ A,
                                               const bf16* __restrict__ Bt,
                                               OutT* __restrict__ C,
                                               int N, int K) {
  __shared__ bf16 As[128 * 64];
  __shared__ bf16 Bs[128 * 64];
  const int tid = threadIdx.x;
  const int wid = tid >> 6, lane = tid & 63;
  const int g = lane >> 4, c = lane & 15;
  const int brow = blockIdx.y * 128, bcol = blockIdx.x * 128;
  const int wr = (wid >> 1) * 64, wc = (wid & 1) * 64;
  f32x4 acc[4][4] = {};

  for (int k0 = 0; k0 < K; k0 += 64) {
#pragma unroll
    for (int i = 0; i < 4; ++i) {
      const int off = i * 4096 + tid * 16;       // byte offset in 16KB tile
      const int row = off >> 7, colb = off & 127;
      gload16((const char*)A + ((size_t)(brow + row) * K + k0) * 2 + colb,
              (char*)As + i * 4096 + wid * 1024);
      gload16((const char*)Bt + ((size_t)(bcol + row) * K + k0) * 2 + colb,
              (char*)Bs + i * 4096 + wid * 1024);
    }
    __syncthreads();
#pragma unroll
    for (int ks = 0; ks < 2; ++ks) {
      bf16x8 af[4], bfr[4];
#pragma unroll
      for (int t = 0; t < 4; ++t) {
        af[t]  = *(const bf16x8*)(As + (wr + t * 16 + c) * 64 + ks * 32 + g * 8);
        bfr[t] = *(const bf16x8*)(Bs + (wc + t * 16 + c) * 64 + ks * 32 + g * 8);
      }
#pragma unroll
      for (int mt = 0; mt < 4; ++mt)
#pragma unroll
        for (int nt = 0; nt < 4; ++nt)
          acc[mt][nt] = __builtin_amdgcn_mfma_f32_16x16x32_bf16(af[mt], bfr[nt], acc[mt][nt], 0, 0, 0);
    }
    __syncthreads();
  }
#pragma unroll
  for (int mt = 0; mt < 4; ++mt)
#pragma unroll
    for (int nt = 0; nt < 4; ++nt)
#pragma unroll
      for (int r = 0; r < 4; ++r) {
        const int row = brow + wr + mt * 16 + 4 * g + r;
        const int col = bcol + wc + nt * 16 + c;
        C[(size_t)row * N + col] = (OutT)acc[mt][nt][r];
      }
}

// ------------------------------------------- RMSNorm + RoPE epilogues
// q in-place within qkvC: [4096][stride], pos = row % 2048
__global__ __launch_bounds__(256) void nrope_q(bf16* __restrict__ q, int stride,
                                               const float* __restrict__ gw,
                                               const float* __restrict__ cache) {
  const int w = blockIdx.x * 4 + (threadIdx.x >> 6);
  const int lane = threadIdx.x & 63;
  const int row = w / 24, head = w % 24;
  const int pos = row & 2047;
  bf16* p = q + (size_t)row * stride + head * 128;
  float x1 = (float)p[lane], x2 = (float)p[64 + lane];
  float ss = x1 * x1 + x2 * x2;
#pragma unroll
  for (int m = 32; m; m >>= 1) ss += __shfl_xor(ss, m);
  const float inv = rsqrtf(ss * (1.0f / 128.0f) + 1e-6f);
  const float xn1 = x1 * inv * gw[lane], xn2 = x2 * inv * gw[64 + lane];
  const float cs = cache[pos * 128 + lane], sn = cache[pos * 128 + 64 + lane];
  p[lane]      = (bf16)(xn1 * cs - xn2 * sn);
  p[64 + lane] = (bf16)(xn2 * cs + xn1 * sn);
}

// k/tk: src [B*S][stride] (+base col) -> kf [b*8+hkv][2560][128] (linear), with norm+rope
__global__ __launch_bounds__(256) void nrope_k(const bf16* __restrict__ src, int stride, int base,
                                               bf16* __restrict__ kf,
                                               const float* __restrict__ gw,
                                               const float* __restrict__ cache,
                                               int S, int key_off) {
  const int w = blockIdx.x * 4 + (threadIdx.x >> 6);
  const int lane = threadIdx.x & 63;
  const int row = w >> 3, hkv = w & 7;
  const int b = row / S, s = row % S;
  const bf16* p = src + (size_t)row * stride + base + hkv * 128;
  float x1 = (float)p[lane], x2 = (float)p[64 + lane];
  float ss = x1 * x1 + x2 * x2;
#pragma unroll
  for (int m = 32; m; m >>= 1) ss += __shfl_xor(ss, m);
  const float inv = rsqrtf(ss * (1.0f / 128.0f) + 1e-6f);
  const float xn1 = x1 * inv * gw[lane], xn2 = x2 * inv * gw[64 + lane];
  const float cs = cache[s * 128 + lane], sn = cache[s * 128 + 64 + lane];
  bf16* o = kf + ((size_t)(b * 8 + hkv) * 2560 + key_off + s) * 128;
  o[lane]      = (bf16)(xn1 * cs - xn2 * sn);
  o[64 + lane] = (bf16)(xn2 * cs + xn1 * sn);
}

// v/tv: src [B*S][stride] (+base col) -> vt [b*8+hkv][128][2560] (transposed)
__global__ __launch_bounds__(256) void transpose_v(const bf16* __restrict__ src, int stride, int base,
                                                   bf16* __restrict__ vtp,
                                                   int S, int key_off) {
  __shared__ bf16 t[32][33];
  const int tid = threadIdx.x;
  const int bh = blockIdx.z;       // b*8+hkv
  const int b = bh >> 3, hkv = bh & 7;
  const int s0 = blockIdx.x * 32, d0 = blockIdx.y * 32;
  const int r = tid >> 3, c4 = (tid & 7) * 4;
  bf16x4 v = *(const bf16x4*)(src + (size_t)(b * S + s0 + r) * stride + base + hkv * 128 + d0 + c4);
  t[r][c4 + 0] = v[0]; t[r][c4 + 1] = v[1]; t[r][c4 + 2] = v[2]; t[r][c4 + 3] = v[3];
  __syncthreads();
  bf16x4 o = { t[c4 + 0][r], t[c4 + 1][r], t[c4 + 2][r], t[c4 + 3][r] };
  *(bf16x4*)(vtp + ((size_t)bh * 128 + d0 + r) * 2560 + key_off + s0 + c4) = o;
}

// ---------------------------------------------------------------- attention
// 768 blocks XCD-chunked; 128 q/block, 4 waves x 32 q (2 qt); NO main-loop LDS/barriers —
// K and V fragments read straight from L2 (XCD remap keeps K/V resident), waves free-run.
__global__ __launch_bounds__(256, 3) void attn_kernel(const bf16* __restrict__ qf,   // [4096][5120]
                                                      const bf16* __restrict__ kf,   // [16][2560][128]
                                                      const bf16* __restrict__ vtp,  // [16][128][2560]
                                                      bf16* __restrict__ attnb) {    // [4096][3072]
  __shared__ bf16 osm[4][32 * 128];  // epilogue staging only
  const int tid = threadIdx.x;
  const int wid = tid >> 6, lane = tid & 63;
  const int g = lane >> 4, c = lane & 15;
  // XCD-chunked remap: 96 consecutive work-ids per XCD -> per-XCD K/V L2-fit
  const int bid0 = blockIdx.x;
  const int bid  = (bid0 & 7) * 96 + (bid0 >> 3);
  const int qb = bid & 15;
  const int h  = (bid >> 4) % 24;
  const int b  = bid / 384;
  const int q0 = qb * 128 + wid * 32;
  const int hkv = h / 3;
  const size_t kbase = (size_t)(b * 8 + hkv) * 2560 * 128;
  const size_t vbase = (size_t)(b * 8 + hkv) * 128 * 2560;

  bf16x8 qfrag[2][4];
#pragma unroll
  for (int qt = 0; qt < 2; ++qt) {
    const size_t qrow = (size_t)(b * 2048 + q0 + qt * 16 + c) * 5120 + h * 128;
#pragma unroll
    for (int kc = 0; kc < 4; ++kc)
      qfrag[qt][kc] = *(const bf16x8*)(qf + qrow + kc * 32 + g * 8);
  }

  f32x4 ot[2][8] = {};
  float mrun[2] = { -__builtin_inff(), -__builtin_inff() };
  float lsum[2] = { 0.f, 0.f };      // per-lane partials, g-reduced in epilogue
  const float sc2 = 0.08838834764831845f * 1.4426950408889634f;  // 1/sqrt(128) * log2(e)

  for (int key0 = 0; key0 < 2560; key0 += 32) {
    // K fragments straight from L2 (issue first — QK needs them)
    bf16x8 kfr0[4], kfr1[4];
#pragma unroll
    for (int kc = 0; kc < 4; ++kc) {
      kfr0[kc] = *(const bf16x8*)(kf + kbase + (size_t)(key0 + c) * 128 + kc * 32 + g * 8);
      kfr1[kc] = *(const bf16x8*)(kf + kbase + (size_t)(key0 + 16 + c) * 128 + kc * 32 + g * 8);
    }
    // V loads issued early (consumed after softmax — latency hidden under QK+softmax)
    bf16x8 vfrag[8];
#pragma unroll
    for (int dt = 0; dt < 8; ++dt)
      vfrag[dt] = *(const bf16x8*)(vtp + vbase + (size_t)(dt * 16 + c) * 2560 + key0 + g * 8);

    // swapped QK^T: S^T = mfma(K, Q); lane holds S[key=4g+r (| +16)][q=c]
    f32x4 s[2][2] = {};
    __builtin_amdgcn_s_setprio(1);
#pragma unroll
    for (int kc = 0; kc < 4; ++kc) {
#pragma unroll
      for (int qt = 0; qt < 2; ++qt) {
        s[qt][0] = __builtin_amdgcn_mfma_f32_16x16x32_bf16(kfr0[kc], qfrag[qt][kc], s[qt][0], 0, 0, 0);
        s[qt][1] = __builtin_amdgcn_mfma_f32_16x16x32_bf16(kfr1[kc], qfrag[qt][kc], s[qt][1], 0, 0, 0);
      }
    }
    __builtin_amdgcn_s_setprio(0);

#pragma unroll
    for (int qt = 0; qt < 2; ++qt) {
      float p0[4], p1[4];
      float tmax = -__builtin_inff();
#pragma unroll
      for (int r = 0; r < 4; ++r) {
        p0[r] = s[qt][0][r] * sc2;
        p1[r] = s[qt][1][r] * sc2;
        tmax = fmaxf(tmax, fmaxf(p0[r], p1[r]));
      }
      // defer-max (T13): per-lane check on common path, no cross-lane reduce
      if (!__all(tmax <= mrun[qt] + 8.f)) {
        tmax = fmaxf(tmax, __shfl_xor(tmax, 16));
        tmax = fmaxf(tmax, __shfl_xor(tmax, 32));
        const float mnew = fmaxf(mrun[qt], tmax);
        const float alpha = fexp2(mrun[qt] - mnew);
        lsum[qt] *= alpha;
#pragma unroll
        for (int dt = 0; dt < 8; ++dt)
#pragma unroll
          for (int r = 0; r < 4; ++r) ot[qt][dt][r] *= alpha;
        mrun[qt] = mnew;
      }
      const float m2 = mrun[qt];
#pragma unroll
      for (int r = 0; r < 4; ++r) {
        p0[r] = fexp2(p0[r] - m2);
        p1[r] = fexp2(p1[r] - m2);
        lsum[qt] += p0[r] + p1[r];
      }
      // packed P redistribution: lane needs P[q=c][key=8g+j]; 8 parallel bpermutes
      const int srcA = 2 * (g & 1) * 16 + c;
      const bool t1 = (g >= 2);
      union { bf16x8 v; unsigned short us[8]; } pf;
#pragma unroll
      for (int r = 0; r < 4; ++r) {
        const unsigned pk = pack2bf(p0[r], p1[r]);
        const unsigned a  = __shfl(pk, srcA);
        const unsigned bb = __shfl(pk, srcA + 16);
        pf.us[r]     = (unsigned short)(t1 ? (a >> 16)  : (a & 0xffff));
        pf.us[4 + r] = (unsigned short)(t1 ? (bb >> 16) : (bb & 0xffff));
      }
      __builtin_amdgcn_s_setprio(1);
#pragma unroll
      for (int dt = 0; dt < 8; ++dt)
        ot[qt][dt] = __builtin_amdgcn_mfma_f32_16x16x32_bf16(vfrag[dt], pf.v, ot[qt][dt], 0, 0, 0);
      __builtin_amdgcn_s_setprio(0);
    }
  }

  // O^T[d][q] -> per-wave 8KB LDS tile (swizzled) -> coalesced global
#pragma unroll
  for (int qt = 0; qt < 2; ++qt) {
    float ls = lsum[qt];
    ls += __shfl_xor(ls, 16);
    ls += __shfl_xor(ls, 32);
    const float inv = 1.0f / ls;
    const int q = qt * 16 + c;
#pragma unroll
    for (int dt = 0; dt < 8; ++dt) {
      uint2 w2;
      w2.x = pack2bf(ot[qt][dt][0] * inv, ot[qt][dt][1] * inv);
      w2.y = pack2bf(ot[qt][dt][2] * inv, ot[qt][dt][3] * inv);
      *(uint2*)((char*)&osm[wid][0] + q * 256 + ((dt * 32 + 8 * g) ^ ((q & 7) << 4))) = w2;
    }
  }
  __syncthreads();
#pragma unroll
  for (int it = 0; it < 8; ++it) {
    const int off = it * 1024 + lane * 16;    // byte in 8KB tile
    const int qrow = off >> 8, colb = off & 255;
    bf16x8 v = *(const bf16x8*)((const char*)&osm[wid][0] + qrow * 256 + (colb ^ ((qrow & 7) << 4)));
    *(bf16x8*)((char*)attnb + ((size_t)(b * 2048 + q0 + qrow) * 3072 + h * 128) * 2 + colb) = v;
  }
}

// ---------------------------------------------------------------- launcher
extern "C" void kernel_launch(void* const* d_in, const int* in_sizes, int n_in,
                              void* d_out, int out_size, void* d_ws, size_t ws_size,
                              hipStream_t stream) {
  const float* hs     = (const float*)d_in[0];
  const float* ehs    = (const float*)d_in[1];
  const float* Wq     = (const float*)d_in[2];
  const float* Wk     = (const float*)d_in[3];
  const float* Wv     = (const float*)d_in[4];
  const float* Wak    = (const float*)d_in[5];
  const float* Wav    = (const float*)d_in[6];
  const float* Wo     = (const float*)d_in[7];
  const float* gq     = (const float*)d_in[8];
  const float* gk     = (const float*)d_in[9];
  const float* gak    = (const float*)d_in[10];
  const float* icache = (const float*)d_in[11];
  const float* tcache = (const float*)d_in[12];

  char* ws = (char*)d_ws;
  bf16* hsb    = (bf16*)(ws + 0);            // 25.2MB; reused as attnb after QKV GEMM
  bf16* Wcomb  = (bf16*)(ws + 25165824);     // [5120][3072] 31.5MB (Wq|Wk|Wv)^T; reused for Wot
  bf16* ehsb   = (bf16*)(ws + 56623104);     // 6.3MB; (ehsb+Wacomb region reused as vt)
  bf16* Wacomb = (bf16*)(ws + 62914560);     // [2048][3072] 12.6MB (Wak|Wav)^T
  bf16* qkvC   = (bf16*)(ws + 75497472);     // [4096][5120] 41.9MB (q|k|v)
  bf16* tC     = (bf16*)(ws + 117440512);    // [1024][2048] 4.2MB (tk|tv)
  bf16* kf     = (bf16*)(ws + 121634816);    // 10.5MB joint K [16][2560][128]
  bf16* Wot    = (bf16*)(ws + 25165824);     // 18.9MB, aliases Wcomb (dead after QKV GEMM)
  bf16* vt     = (bf16*)(ws + 56623104);     // 10.5MB joint V^T, aliases ehsb+Wacomb (dead after tGEMM)
  bf16* attnb  = hsb;                        // aliases hsb (dead after QKV GEMM)
  // max ws offset: 132,120,576 bytes

  cvt_bf16<<<6144, 256, 0, stream>>>(hs, hsb, 1572864);
  cvt_bf16<<<1536, 256, 0, stream>>>(ehs, ehsb, 393216);
  tcvt<<<dim3(96, 96), 256, 0, stream>>>(Wq,  Wcomb,                3072, 3072);
  tcvt<<<dim3(32, 96), 256, 0, stream>>>(Wk,  Wcomb + 3072 * 3072,  3072, 1024);
  tcvt<<<dim3(32, 96), 256, 0, stream>>>(Wv,  Wcomb + 4096 * 3072,  3072, 1024);
  tcvt<<<dim3(32, 96), 256, 0, stream>>>(Wak, Wacomb,               3072, 1024);
  tcvt<<<dim3(32, 96), 256, 0, stream>>>(Wav, Wacomb + 1024 * 3072, 3072, 1024);

  // fused QKV GEMM: [4096][3072] x [5120][3072]^T -> [4096][5120]
  gemm_bt<bf16><<<dim3(40, 32), 256, 0, stream>>>(hsb,  Wcomb,  qkvC, 5120, 3072);
  // fused tK/tV GEMM: [1024][3072] x [2048][3072]^T -> [1024][2048]
  gemm_bt<bf16><<<dim3(16, 8),  256, 0, stream>>>(ehsb, Wacomb, tC,   2048, 3072);

  // Wo transpose-convert AFTER QKV GEMM (reuses Wcomb region)
  tcvt<<<dim3(96, 96), 256, 0, stream>>>(Wo, Wot, 3072, 3072);

  nrope_q<<<24576, 256, 0, stream>>>(qkvC, 5120, gq, icache);
  nrope_k<<<8192, 256, 0, stream>>>(qkvC, 5120, 3072, kf, gk,  icache, 2048, 0);
  nrope_k<<<2048, 256, 0, stream>>>(tC,   2048, 0,    kf, gak, tcache, 512,  2048);
  transpose_v<<<dim3(64, 4, 16), 256, 0, stream>>>(qkvC, 5120, 4096, vt, 2048, 0);
  transpose_v<<<dim3(16, 4, 16), 256, 0, stream>>>(tC,   2048, 1024, vt, 512,  2048);

  attn_kernel<<<768, 256, 0, stream>>>(qkvC, kf, vt, attnb);

  gemm_bt<float><<<dim3(24, 32), 256, 0, stream>>>(attnb, Wot, (float*)d_out, 3072, 3072);
}

// Round 7
// 667.690 us; speedup vs baseline: 1.6782x; 1.3877x over previous
//
#include <hip/hip_runtime.h>
#include <hip/hip_bf16.h>
#include <math.h>

typedef __bf16 bf16;
typedef __bf16 bf16x4 __attribute__((ext_vector_type(4)));
typedef __bf16 bf16x8 __attribute__((ext_vector_type(8)));
typedef float  f32x4  __attribute__((ext_vector_type(4)));

typedef __attribute__((address_space(1))) void gvoid_t;
typedef __attribute__((address_space(3))) void lvoid_t;

static __device__ __forceinline__ void gload16(const void* g, void* l) {
  // async global->LDS, 16B per lane; LDS dest wave-uniform base (HW adds lane*16)
  __builtin_amdgcn_global_load_lds((gvoid_t*)g, (lvoid_t*)l, 16, 0, 0);
}

static __device__ __forceinline__ float fexp2(float x) {
  return __builtin_amdgcn_exp2f(x);   // v_exp_f32: 2^x
}

static __device__ __forceinline__ unsigned pack2bf(float lo, float hi) {
  unsigned short l = __builtin_bit_cast(unsigned short, (bf16)lo);
  unsigned short h = __builtin_bit_cast(unsigned short, (bf16)hi);
  return ((unsigned)h << 16) | (unsigned)l;
}

// ---------------------------------------------------------------- converts
__global__ __launch_bounds__(256) void cvt_bf16(const float* __restrict__ in,
                                                bf16* __restrict__ out, int n8) {
  int i = blockIdx.x * 256 + threadIdx.x;
  if (i >= n8) return;
  const float4* p = (const float4*)(in + (size_t)i * 8);
  float4 v0 = p[0], v1 = p[1];
  bf16x8 o;
  o[0] = (bf16)v0.x; o[1] = (bf16)v0.y; o[2] = (bf16)v0.z; o[3] = (bf16)v0.w;
  o[4] = (bf16)v1.x; o[5] = (bf16)v1.y; o[6] = (bf16)v1.z; o[7] = (bf16)v1.w;
  *(bf16x8*)(out + (size_t)i * 8) = o;
}

// W [K][N] fp32 -> Wt [N][K] bf16 (32x32 LDS tiles)
__global__ __launch_bounds__(256) void tcvt(const float* __restrict__ W,
                                            bf16* __restrict__ Wt, int K, int N) {
  __shared__ float t[32][33];
  const int tid = threadIdx.x;
  const int r = tid >> 3, c4 = (tid & 7) * 4;
  const size_t grow = (size_t)(blockIdx.y * 32 + r);
  float4 v = *(const float4*)(W + grow * N + blockIdx.x * 32 + c4);
  t[r][c4 + 0] = v.x; t[r][c4 + 1] = v.y; t[r][c4 + 2] = v.z; t[r][c4 + 3] = v.w;
  __syncthreads();
  bf16x4 o = { (bf16)t[c4 + 0][r], (bf16)t[c4 + 1][r], (bf16)t[c4 + 2][r], (bf16)t[c4 + 3][r] };
  *(bf16x4*)(Wt + (size_t)(blockIdx.x * 32 + r) * K + blockIdx.y * 32 + c4) = o;
}

// ---------------------------------------------------------------- GEMM (NT)
// C[M][N] = A[M][K] * Bt[N][K]^T ; 128x128 tile, BK=64, 4 waves, m97 structure
template <typename OutT>
__global__ __launch_bounds__(256) void gemm_bt(const bf16* __restrict__ A,
                                               const bf16* __restrict__ Bt,
                                               OutT* __restrict__ C,
                                               int N, int K) {
  __shared__ bf16 As[128 * 64];
  __shared__ bf16 Bs[128 * 64];
  const int tid = threadIdx.x;
  const int wid = tid >> 6, lane = tid & 63;
  const int g = lane >> 4, c = lane & 15;
  const int brow = blockIdx.y * 128, bcol = blockIdx.x * 128;
  const int wr = (wid >> 1) * 64, wc = (wid & 1) * 64;
  f32x4 acc[4][4] = {};

  for (int k0 = 0; k0 < K; k0 += 64) {
#pragma unroll
    for (int i = 0; i < 4; ++i) {
      const int off = i * 4096 + tid * 16;       // byte offset in 16KB tile
      const int row = off >> 7, colb = off & 127;
      gload16((const char*)A + ((size_t)(brow + row) * K + k0) * 2 + colb,
              (char*)As + i * 4096 + wid * 1024);
      gload16((const char*)Bt + ((size_t)(bcol + row) * K + k0) * 2 + colb,
              (char*)Bs + i * 4096 + wid * 1024);
    }
    __syncthreads();
#pragma unroll
    for (int ks = 0; ks < 2; ++ks) {
      bf16x8 af[4], bfr[4];
#pragma unroll
      for (int t = 0; t < 4; ++t) {
        af[t]  = *(const bf16x8*)(As + (wr + t * 16 + c) * 64 + ks * 32 + g * 8);
        bfr[t] = *(const bf16x8*)(Bs + (wc + t * 16 + c) * 64 + ks * 32 + g * 8);
      }
#pragma unroll
      for (int mt = 0; mt < 4; ++mt)
#pragma unroll
        for (int nt = 0; nt < 4; ++nt)
          acc[mt][nt] = __builtin_amdgcn_mfma_f32_16x16x32_bf16(af[mt], bfr[nt], acc[mt][nt], 0, 0, 0);
    }
    __syncthreads();
  }
#pragma unroll
  for (int mt = 0; mt < 4; ++mt)
#pragma unroll
    for (int nt = 0; nt < 4; ++nt)
#pragma unroll
      for (int r = 0; r < 4; ++r) {
        const int row = brow + wr + mt * 16 + 4 * g + r;
        const int col = bcol + wc + nt * 16 + c;
        C[(size_t)row * N + col] = (OutT)acc[mt][nt][r];
      }
}

// ------------------------------------------- RMSNorm + RoPE epilogues
// q in-place within qkvC: [4096][stride]; output pre-scaled by 1/sqrt(D)*log2(e)
__global__ __launch_bounds__(256) void nrope_q(bf16* __restrict__ q, int stride,
                                               const float* __restrict__ gw,
                                               const float* __restrict__ cache) {
  const float SC = 0.08838834764831845f * 1.4426950408889634f;
  const int w = blockIdx.x * 4 + (threadIdx.x >> 6);
  const int lane = threadIdx.x & 63;
  const int row = w / 24, head = w % 24;
  const int pos = row & 2047;
  bf16* p = q + (size_t)row * stride + head * 128;
  float x1 = (float)p[lane], x2 = (float)p[64 + lane];
  float ss = x1 * x1 + x2 * x2;
#pragma unroll
  for (int m = 32; m; m >>= 1) ss += __shfl_xor(ss, m);
  const float inv = rsqrtf(ss * (1.0f / 128.0f) + 1e-6f);
  const float xn1 = x1 * inv * gw[lane], xn2 = x2 * inv * gw[64 + lane];
  const float cs = cache[pos * 128 + lane] * SC, sn = cache[pos * 128 + 64 + lane] * SC;
  p[lane]      = (bf16)(xn1 * cs - xn2 * sn);
  p[64 + lane] = (bf16)(xn2 * cs + xn1 * sn);
}

// k/tk: src [B*S][stride] (+base col) -> kf [b*8+hkv][2560][128] SWIZZLED (16B slot ^ (key&7))
__global__ __launch_bounds__(256) void nrope_k(const bf16* __restrict__ src, int stride, int base,
                                               bf16* __restrict__ kf,
                                               const float* __restrict__ gw,
                                               const float* __restrict__ cache,
                                               int S, int key_off) {
  const int w = blockIdx.x * 4 + (threadIdx.x >> 6);
  const int lane = threadIdx.x & 63;
  const int row = w >> 3, hkv = w & 7;
  const int b = row / S, s = row % S;
  const bf16* p = src + (size_t)row * stride + base + hkv * 128;
  float x1 = (float)p[lane], x2 = (float)p[64 + lane];
  float ss = x1 * x1 + x2 * x2;
#pragma unroll
  for (int m = 32; m; m >>= 1) ss += __shfl_xor(ss, m);
  const float inv = rsqrtf(ss * (1.0f / 128.0f) + 1e-6f);
  const float xn1 = x1 * inv * gw[lane], xn2 = x2 * inv * gw[64 + lane];
  const float cs = cache[s * 128 + lane], sn = cache[s * 128 + 64 + lane];
  bf16* o = kf + ((size_t)(b * 8 + hkv) * 2560 + key_off + s) * 128;
  const int dsw = lane ^ ((s & 7) << 3);     // key_off is 0 mod 8, so key&7 == s&7
  o[dsw]      = (bf16)(xn1 * cs - xn2 * sn);
  o[64 + dsw] = (bf16)(xn2 * cs + xn1 * sn);
}

// v/tv: src [B*S][stride] (+base col) -> vt [b*8+hkv][128][2560] (transposed, linear)
__global__ __launch_bounds__(256) void transpose_v(const bf16* __restrict__ src, int stride, int base,
                                                   bf16* __restrict__ vtp,
                                                   int S, int key_off) {
  __shared__ bf16 t[32][33];
  const int tid = threadIdx.x;
  const int bh = blockIdx.z;       // b*8+hkv
  const int b = bh >> 3, hkv = bh & 7;
  const int s0 = blockIdx.x * 32, d0 = blockIdx.y * 32;
  const int r = tid >> 3, c4 = (tid & 7) * 4;
  bf16x4 v = *(const bf16x4*)(src + (size_t)(b * S + s0 + r) * stride + base + hkv * 128 + d0 + c4);
  t[r][c4 + 0] = v[0]; t[r][c4 + 1] = v[1]; t[r][c4 + 2] = v[2]; t[r][c4 + 3] = v[3];
  __syncthreads();
  bf16x4 o = { t[c4 + 0][r], t[c4 + 1][r], t[c4 + 2][r], t[c4 + 3][r] };
  *(bf16x4*)(vtp + ((size_t)bh * 128 + d0 + r) * 2560 + key_off + s0 + c4) = o;
}

// ---------------------------------------------------------------- attention
// 768 blocks XCD-chunked; 128 q/block, 4 waves x 32 q; KVBLK=64; K+V LDS dbuf staged.
__global__ __launch_bounds__(256, 2) void attn_kernel(const bf16* __restrict__ qf,   // [4096][5120]
                                                      const bf16* __restrict__ kfsw, // [16][2560][128] swz
                                                      const bf16* __restrict__ vtp,  // [16][128][2560]
                                                      bf16* __restrict__ attnb) {    // [4096][3072]
  __shared__ bf16 Ks[2][64 * 128];   // 2 x 16KB K tiles (global pre-swizzled, linear copy)
  __shared__ bf16 Vs[2][128 * 64];   // 2 x 16KB V^T tiles (swizzled at stage)
  __shared__ char Ps[4][1280];       // per-wave P staging, 16 rows x 80B (padded)
  const int tid = threadIdx.x;
  const int wid = tid >> 6, lane = tid & 63;
  const int g = lane >> 4, c = lane & 15;
  // XCD-chunked remap: 96 consecutive work-ids per XCD -> per-XCD K/V locality
  const int bid0 = blockIdx.x;
  const int bid  = (bid0 & 7) * 96 + (bid0 >> 3);
  const int qb = bid & 15;
  const int h  = (bid >> 4) % 24;
  const int b  = bid / 384;
  const int q0 = qb * 128 + wid * 32;
  const int hkv = h / 3;
  const char* kfB = (const char*)kfsw + (size_t)(b * 8 + hkv) * 2560 * 256;
  const char* vtB = (const char*)vtp  + (size_t)(b * 8 + hkv) * 128 * 5120;

  bf16x8 qfrag[2][4];
#pragma unroll
  for (int qt = 0; qt < 2; ++qt) {
    const size_t qrow = (size_t)(b * 2048 + q0 + qt * 16 + c) * 5120 + h * 128;
#pragma unroll
    for (int kc = 0; kc < 4; ++kc)
      qfrag[qt][kc] = *(const bf16x8*)(qf + qrow + kc * 32 + g * 8);
  }

  f32x4 ot[2][8] = {};
  float mrun[2] = { -__builtin_inff(), -__builtin_inff() };
  float lsum[2] = { 0.f, 0.f };      // per-lane partials, g-reduced in epilogue

  // stage one 64-key tile: K 16KB (4 gload16/wave) + V 16KB (4 gload16/wave)
  auto stage = [&](int key0, int buf) {
    {  // K: rows wid*16 .. +15, linear copy of pre-swizzled rows
      char* ldst = (char*)&Ks[buf][0] + wid * 4096;
      const char* gsrc = kfB + (size_t)(key0 + wid * 16) * 256
                       + (lane >> 4) * 256 + (lane & 15) * 16;
#pragma unroll
      for (int j = 0; j < 4; ++j)
        gload16(gsrc + j * 1024, ldst + j * 1024);
    }
    {  // V: rows (d) wid*32 .. +31; store slot = actual_slot ^ (d&7)
      char* ldst = (char*)&Vs[buf][0] + wid * 4096;
      const int r8 = lane >> 3, c8 = lane & 7;
      const char* gsrc = vtB + (size_t)(wid * 32 + r8) * 5120 + (size_t)key0 * 2
                       + ((c8 ^ r8) * 16);
#pragma unroll
      for (int j = 0; j < 4; ++j)
        gload16(gsrc + (size_t)j * 8 * 5120, ldst + j * 1024);
    }
  };

  stage(0, 0);
  __syncthreads();

  for (int it = 0; it < 40; ++it) {
    const int cur = it & 1;
    if (it + 1 < 40) stage((it + 1) * 64, cur ^ 1);

    const char* Kb = (const char*)&Ks[cur][0];
    const char* Vb = (const char*)&Vs[cur][0];

#pragma unroll
    for (int kb = 0; kb < 2; ++kb) {
      // QK^T (swapped): lane holds S[key_local = kb*32 + 4g+r (|+16)][q=c]
      f32x4 s[2][2] = {};
      __builtin_amdgcn_s_setprio(1);
#pragma unroll
      for (int kc = 0; kc < 4; ++kc) {
        const int bsw = (kc * 64 + g * 16) ^ ((c & 7) << 4);
        bf16x8 a0 = *(const bf16x8*)(Kb + (kb * 32 + c) * 256 + bsw);
        bf16x8 a1 = *(const bf16x8*)(Kb + (kb * 32 + 16 + c) * 256 + bsw);
#pragma unroll
        for (int qt = 0; qt < 2; ++qt) {
          s[qt][0] = __builtin_amdgcn_mfma_f32_16x16x32_bf16(a0, qfrag[qt][kc], s[qt][0], 0, 0, 0);
          s[qt][1] = __builtin_amdgcn_mfma_f32_16x16x32_bf16(a1, qfrag[qt][kc], s[qt][1], 0, 0, 0);
        }
      }
      __builtin_amdgcn_s_setprio(0);

      // V fragments for this key half (from LDS, swizzled)
      bf16x8 vfrag[8];
#pragma unroll
      for (int dt = 0; dt < 8; ++dt)
        vfrag[dt] = *(const bf16x8*)(Vb + (dt * 16 + c) * 128 + (((kb * 4 + g) ^ (c & 7)) * 16));

#pragma unroll
      for (int qt = 0; qt < 2; ++qt) {
        float p0[4], p1[4];
        float tmax = -__builtin_inff();
#pragma unroll
        for (int r = 0; r < 4; ++r) {
          p0[r] = s[qt][0][r];           // already log2-scaled (folded into rope)
          p1[r] = s[qt][1][r];
          tmax = fmaxf(tmax, fmaxf(p0[r], p1[r]));
        }
        // defer-max (T13): per-lane check on common path
        if (!__all(tmax <= mrun[qt] + 8.f)) {
          tmax = fmaxf(tmax, __shfl_xor(tmax, 16));
          tmax = fmaxf(tmax, __shfl_xor(tmax, 32));
          const float mnew = fmaxf(mrun[qt], tmax);
          const float alpha = fexp2(mrun[qt] - mnew);
          lsum[qt] *= alpha;
#pragma unroll
          for (int dt = 0; dt < 8; ++dt)
#pragma unroll
            for (int r = 0; r < 4; ++r) ot[qt][dt][r] *= alpha;
          mrun[qt] = mnew;
        }
        const float m2 = mrun[qt];
#pragma unroll
        for (int r = 0; r < 4; ++r) {
          p0[r] = fexp2(p0[r] - m2);
          p1[r] = fexp2(p1[r] - m2);
          lsum[qt] += p0[r] + p1[r];
        }
        // P redistribution via per-wave LDS tile: row q=c (80B stride), key*2 bytes
        unsigned* pw = (unsigned*)(&Ps[wid][0] + c * 80);
        pw[2 * g + 0]     = pack2bf(p0[0], p0[1]);
        pw[2 * g + 1]     = pack2bf(p0[2], p0[3]);
        pw[8 + 2 * g + 0] = pack2bf(p1[0], p1[1]);
        pw[8 + 2 * g + 1] = pack2bf(p1[2], p1[3]);
        bf16x8 pf = *(const bf16x8*)(&Ps[wid][0] + c * 80 + g * 16);  // keys 8g..8g+7
        __builtin_amdgcn_s_setprio(1);
#pragma unroll
        for (int dt = 0; dt < 8; ++dt)
          ot[qt][dt] = __builtin_amdgcn_mfma_f32_16x16x32_bf16(vfrag[dt], pf, ot[qt][dt], 0, 0, 0);
        __builtin_amdgcn_s_setprio(0);
      }
    }
    __syncthreads();
  }

  // O^T[d][q] -> per-wave 8KB LDS tile (aliases Ks, dead now; swizzled) -> coalesced global
  char* osm = (char*)&Ks[0][0] + wid * 8192;
#pragma unroll
  for (int qt = 0; qt < 2; ++qt) {
    float ls = lsum[qt];
    ls += __shfl_xor(ls, 16);
    ls += __shfl_xor(ls, 32);
    const float inv = 1.0f / ls;
    const int q = qt * 16 + c;
#pragma unroll
    for (int dt = 0; dt < 8; ++dt) {
      uint2 w2;
      w2.x = pack2bf(ot[qt][dt][0] * inv, ot[qt][dt][1] * inv);
      w2.y = pack2bf(ot[qt][dt][2] * inv, ot[qt][dt][3] * inv);
      *(uint2*)(osm + q * 256 + ((dt * 32 + 8 * g) ^ ((q & 7) << 4))) = w2;
    }
  }
  __syncthreads();
#pragma unroll
  for (int it = 0; it < 8; ++it) {
    const int off = it * 1024 + lane * 16;    // byte in 8KB tile
    const int qrow = off >> 8, colb = off & 255;
    bf16x8 v = *(const bf16x8*)(osm + qrow * 256 + (colb ^ ((qrow & 7) << 4)));
    *(bf16x8*)((char*)attnb + ((size_t)(b * 2048 + q0 + qrow) * 3072 + h * 128) * 2 + colb) = v;
  }
}

// ---------------------------------------------------------------- launcher
extern "C" void kernel_launch(void* const* d_in, const int* in_sizes, int n_in,
                              void* d_out, int out_size, void* d_ws, size_t ws_size,
                              hipStream_t stream) {
  const float* hs     = (const float*)d_in[0];
  const float* ehs    = (const float*)d_in[1];
  const float* Wq     = (const float*)d_in[2];
  const float* Wk     = (const float*)d_in[3];
  const float* Wv     = (const float*)d_in[4];
  const float* Wak    = (const float*)d_in[5];
  const float* Wav    = (const float*)d_in[6];
  const float* Wo     = (const float*)d_in[7];
  const float* gq     = (const float*)d_in[8];
  const float* gk     = (const float*)d_in[9];
  const float* gak    = (const float*)d_in[10];
  const float* icache = (const float*)d_in[11];
  const float* tcache = (const float*)d_in[12];

  char* ws = (char*)d_ws;
  bf16* hsb    = (bf16*)(ws + 0);            // 25.2MB; reused as attnb after QKV GEMM
  bf16* Wcomb  = (bf16*)(ws + 25165824);     // [5120][3072] 31.5MB (Wq|Wk|Wv)^T; reused for Wot
  bf16* ehsb   = (bf16*)(ws + 56623104);     // 6.3MB; (ehsb+Wacomb region reused as vt)
  bf16* Wacomb = (bf16*)(ws + 62914560);     // [2048][3072] 12.6MB (Wak|Wav)^T
  bf16* qkvC   = (bf16*)(ws + 75497472);     // [4096][5120] 41.9MB (q|k|v)
  bf16* tC     = (bf16*)(ws + 117440512);    // [1024][2048] 4.2MB (tk|tv)
  bf16* kf     = (bf16*)(ws + 121634816);    // 10.5MB joint K [16][2560][128] (swizzled)
  bf16* Wot    = (bf16*)(ws + 25165824);     // 18.9MB, aliases Wcomb (dead after QKV GEMM)
  bf16* vt     = (bf16*)(ws + 56623104);     // 10.5MB joint V^T, aliases ehsb+Wacomb (dead after tGEMM)
  bf16* attnb  = hsb;                        // aliases hsb (dead after QKV GEMM)
  // max ws offset: 132,120,576 bytes

  cvt_bf16<<<6144, 256, 0, stream>>>(hs, hsb, 1572864);
  cvt_bf16<<<1536, 256, 0, stream>>>(ehs, ehsb, 393216);
  tcvt<<<dim3(96, 96), 256, 0, stream>>>(Wq,  Wcomb,                3072, 3072);
  tcvt<<<dim3(32, 96), 256, 0, stream>>>(Wk,  Wcomb + 3072 * 3072,  3072, 1024);
  tcvt<<<dim3(32, 96), 256, 0, stream>>>(Wv,  Wcomb + 4096 * 3072,  3072, 1024);
  tcvt<<<dim3(32, 96), 256, 0, stream>>>(Wak, Wacomb,               3072, 1024);
  tcvt<<<dim3(32, 96), 256, 0, stream>>>(Wav, Wacomb + 1024 * 3072, 3072, 1024);

  // fused QKV GEMM: [4096][3072] x [5120][3072]^T -> [4096][5120]
  gemm_bt<bf16><<<dim3(40, 32), 256, 0, stream>>>(hsb,  Wcomb,  qkvC, 5120, 3072);
  // fused tK/tV GEMM: [1024][3072] x [2048][3072]^T -> [1024][2048]
  gemm_bt<bf16><<<dim3(16, 8),  256, 0, stream>>>(ehsb, Wacomb, tC,   2048, 3072);

  // Wo transpose-convert AFTER QKV GEMM (reuses Wcomb region)
  tcvt<<<dim3(96, 96), 256, 0, stream>>>(Wo, Wot, 3072, 3072);

  nrope_q<<<24576, 256, 0, stream>>>(qkvC, 5120, gq, icache);
  nrope_k<<<8192, 256, 0, stream>>>(qkvC, 5120, 3072, kf, gk,  icache, 2048, 0);
  nrope_k<<<2048, 256, 0, stream>>>(tC,   2048, 0,    kf, gak, tcache, 512,  2048);
  transpose_v<<<dim3(64, 4, 16), 256, 0, stream>>>(qkvC, 5120, 4096, vt, 2048, 0);
  transpose_v<<<dim3(16, 4, 16), 256, 0, stream>>>(tC,   2048, 1024, vt, 512,  2048);

  attn_kernel<<<768, 256, 0, stream>>>(qkvC, kf, vt, attnb);

  gemm_bt<float><<<dim3(24, 32), 256, 0, stream>>>(attnb, Wot, (float*)d_out, 3072, 3072);
}

// Round 8
// 610.726 us; speedup vs baseline: 1.8347x; 1.0933x over previous
//
#include <hip/hip_runtime.h>
#include <hip/hip_bf16.h>
#include <math.h>

typedef __bf16 bf16;
typedef __bf16 bf16x4 __attribute__((ext_vector_type(4)));
typedef __bf16 bf16x8 __attribute__((ext_vector_type(8)));
typedef float  f32x4  __attribute__((ext_vector_type(4)));

typedef __attribute__((address_space(1))) void gvoid_t;
typedef __attribute__((address_space(3))) void lvoid_t;

static __device__ __forceinline__ void gload16(const void* g, void* l) {
  // async global->LDS, 16B per lane; LDS dest wave-uniform base (HW adds lane*16)
  __builtin_amdgcn_global_load_lds((gvoid_t*)g, (lvoid_t*)l, 16, 0, 0);
}

static __device__ __forceinline__ float fexp2(float x) {
  return __builtin_amdgcn_exp2f(x);   // v_exp_f32: 2^x
}

static __device__ __forceinline__ unsigned pack2bf(float lo, float hi) {
  unsigned short l = __builtin_bit_cast(unsigned short, (bf16)lo);
  unsigned short h = __builtin_bit_cast(unsigned short, (bf16)hi);
  return ((unsigned)h << 16) | (unsigned)l;
}

// ---------------------------------------------------------------- converts
__global__ __launch_bounds__(256) void cvt_bf16(const float* __restrict__ in,
                                                bf16* __restrict__ out, int n8) {
  int i = blockIdx.x * 256 + threadIdx.x;
  if (i >= n8) return;
  const float4* p = (const float4*)(in + (size_t)i * 8);
  float4 v0 = p[0], v1 = p[1];
  bf16x8 o;
  o[0] = (bf16)v0.x; o[1] = (bf16)v0.y; o[2] = (bf16)v0.z; o[3] = (bf16)v0.w;
  o[4] = (bf16)v1.x; o[5] = (bf16)v1.y; o[6] = (bf16)v1.z; o[7] = (bf16)v1.w;
  *(bf16x8*)(out + (size_t)i * 8) = o;
}

// W [K][N] fp32 -> Wt [N][K] bf16 (32x32 LDS tiles)
__global__ __launch_bounds__(256) void tcvt(const float* __restrict__ W,
                                            bf16* __restrict__ Wt, int K, int N) {
  __shared__ float t[32][33];
  const int tid = threadIdx.x;
  const int r = tid >> 3, c4 = (tid & 7) * 4;
  const size_t grow = (size_t)(blockIdx.y * 32 + r);
  float4 v = *(const float4*)(W + grow * N + blockIdx.x * 32 + c4);
  t[r][c4 + 0] = v.x; t[r][c4 + 1] = v.y; t[r][c4 + 2] = v.z; t[r][c4 + 3] = v.w;
  __syncthreads();
  bf16x4 o = { (bf16)t[c4 + 0][r], (bf16)t[c4 + 1][r], (bf16)t[c4 + 2][r], (bf16)t[c4 + 3][r] };
  *(bf16x4*)(Wt + (size_t)(blockIdx.x * 32 + r) * K + blockIdx.y * 32 + c4) = o;
}

// ---------------------------------------------------------------- GEMM (NT, small shapes)
// C[M][N] = A[M][K] * Bt[N][K]^T ; 128x128 tile, BK=64, 4 waves, m97 structure
template <typename OutT>
__global__ __launch_bounds__(256) void gemm_bt(const bf16* __restrict__ A,
                                               const bf16* __restrict__ Bt,
                                               OutT* __restrict__ C,
                                               int N, int K) {
  __shared__ bf16 As[128 * 64];
  __shared__ bf16 Bs[128 * 64];
  const int tid = threadIdx.x;
  const int wid = tid >> 6, lane = tid & 63;
  const int g = lane >> 4, c = lane & 15;
  const int brow = blockIdx.y * 128, bcol = blockIdx.x * 128;
  const int wr = (wid >> 1) * 64, wc = (wid & 1) * 64;
  f32x4 acc[4][4] = {};

  for (int k0 = 0; k0 < K; k0 += 64) {
#pragma unroll
    for (int i = 0; i < 4; ++i) {
      const int off = i * 4096 + tid * 16;
      const int row = off >> 7, colb = off & 127;
      gload16((const char*)A + ((size_t)(brow + row) * K + k0) * 2 + colb,
              (char*)As + i * 4096 + wid * 1024);
      gload16((const char*)Bt + ((size_t)(bcol + row) * K + k0) * 2 + colb,
              (char*)Bs + i * 4096 + wid * 1024);
    }
    __syncthreads();
#pragma unroll
    for (int ks = 0; ks < 2; ++ks) {
      bf16x8 af[4], bfr[4];
#pragma unroll
      for (int t = 0; t < 4; ++t) {
        af[t]  = *(const bf16x8*)(As + (wr + t * 16 + c) * 64 + ks * 32 + g * 8);
        bfr[t] = *(const bf16x8*)(Bs + (wc + t * 16 + c) * 64 + ks * 32 + g * 8);
      }
#pragma unroll
      for (int mt = 0; mt < 4; ++mt)
#pragma unroll
        for (int nt = 0; nt < 4; ++nt)
          acc[mt][nt] = __builtin_amdgcn_mfma_f32_16x16x32_bf16(af[mt], bfr[nt], acc[mt][nt], 0, 0, 0);
    }
    __syncthreads();
  }
#pragma unroll
  for (int mt = 0; mt < 4; ++mt)
#pragma unroll
    for (int nt = 0; nt < 4; ++nt)
#pragma unroll
      for (int r = 0; r < 4; ++r) {
        const int row = brow + wr + mt * 16 + 4 * g + r;
        const int col = bcol + wc + nt * 16 + c;
        C[(size_t)row * N + col] = (OutT)acc[mt][nt][r];
      }
}

// ---------------------------------------------------------------- GEMM (NT, 8-phase pipelined)
// BM=128 x BN=256, K-half(32) staging units, 4-slot rotation, counted vmcnt(6).
// 8 waves (2M x 4N), 512 threads, 96KB LDS, 1 block/CU.
// LDS layout per unit: 128B "lines" = 2 rows; 16B-slot s8 = ((row&1)*4 + g) XOR (line&7)
// -> wave-wide reads spread uniformly over all 32 banks (T2); staged via pre-swizzled
// global source + linear gload_lds dest (rule #21).
template <typename OutT>
__global__ __launch_bounds__(512, 2) void gemm8(const bf16* __restrict__ A,
                                                const bf16* __restrict__ Bt,
                                                OutT* __restrict__ C,
                                                int N, int K, int NBX) {
  __shared__ char As[4 * 8192];    // 4 K-half slots x (128 rows x 32 K)
  __shared__ char Bs[4 * 16384];   // 4 K-half slots x (256 rows x 32 K)
  const int tid = threadIdx.x;
  const int lane = tid & 63, wid = tid >> 6;
  const int g = lane >> 4, c = lane & 15;
  const int wm = wid >> 2, wn = wid & 3;
  // XCD-chunked bijective remap (gridDim.x % 8 == 0); bx fastest -> compact per-XCD 2D chunk
  const int cpx = gridDim.x >> 3;
  const int wgid = ((int)blockIdx.x & 7) * cpx + ((int)blockIdx.x >> 3);
  const int by = wgid / NBX, bx = wgid % NBX;
  const int brow = by * 128, bcol = bx * 256;
  const int KH = K >> 5;           // # K-halves

  f32x4 acc[4][4] = {};

  // --- stage addressing (per-thread, kh-invariant): LDS linear byte L -> global (row, g)
  // A (one 8KB call): L = wid*1024 + lane*16
  int LA = wid * 1024 + lane * 16;
  int lnA = LA >> 7;
  int sA = ((LA >> 4) & 7) ^ (lnA & 7);
  const char* Abase = (const char*)(A + (size_t)(brow + lnA * 2 + (sA >> 2)) * K + (sA & 3) * 8);
  // B (two 8KB calls)
  int LB0 = wid * 1024 + lane * 16;
  int ln0 = LB0 >> 7;
  int s0 = ((LB0 >> 4) & 7) ^ (ln0 & 7);
  const char* Bbase0 = (const char*)(Bt + (size_t)(bcol + ln0 * 2 + (s0 >> 2)) * K + (s0 & 3) * 8);
  int LB1 = 8192 + wid * 1024 + lane * 16;
  int ln1 = LB1 >> 7;
  int s1 = ((LB1 >> 4) & 7) ^ (ln1 & 7);
  const char* Bbase1 = (const char*)(Bt + (size_t)(bcol + ln1 * 2 + (s1 >> 2)) * K + (s1 & 3) * 8);

  auto stage = [&](int kh, int slot) {   // 3 x gload16 = one K-half unit (A 8KB + B 16KB)
    const size_t koff = (size_t)kh * 64;  // kh*32 elems * 2B
    gload16(Abase + koff, As + slot * 8192 + wid * 1024);
    gload16(Bbase0 + koff, Bs + slot * 16384 + wid * 1024);
    gload16(Bbase1 + koff, Bs + slot * 16384 + 8192 + wid * 1024);
  };

  // --- fragment read offsets (swizzled), kh-invariant
  int offA[4], offB[4];
#pragma unroll
  for (int mf = 0; mf < 4; ++mf) {
    const int row = wm * 64 + mf * 16 + c;
    const int ln = row >> 1;
    const int s = (((row & 1) << 2) | g) ^ (ln & 7);
    offA[mf] = ln * 128 + s * 16;
  }
#pragma unroll
  for (int nf = 0; nf < 4; ++nf) {
    const int row = wn * 64 + nf * 16 + c;
    const int ln = row >> 1;
    const int s = (((row & 1) << 2) | g) ^ (ln & 7);
    offB[nf] = ln * 128 + s * 16;
  }

#define GEMM8_PHASE(PHI, KH3)                                                     \
  {                                                                               \
    bf16x8 af[4], bfr[4];                                                         \
    _Pragma("unroll") for (int mf = 0; mf < 4; ++mf)                              \
      af[mf] = *(const bf16x8*)(As + (PHI) * 8192 + offA[mf]);                    \
    _Pragma("unroll") for (int nf = 0; nf < 4; ++nf)                              \
      bfr[nf] = *(const bf16x8*)(Bs + (PHI) * 16384 + offB[nf]);                  \
    stage((KH3), ((PHI) + 3) & 3);                                                \
    asm volatile("s_waitcnt vmcnt(6)" ::: "memory");                              \
    __builtin_amdgcn_s_barrier();                                                 \
    asm volatile("s_waitcnt lgkmcnt(0)" ::: "memory");                            \
    __builtin_amdgcn_sched_barrier(0);                                            \
    __builtin_amdgcn_s_setprio(1);                                                \
    _Pragma("unroll") for (int mf = 0; mf < 4; ++mf)                              \
      _Pragma("unroll") for (int nf = 0; nf < 4; ++nf)                            \
        acc[mf][nf] = __builtin_amdgcn_mfma_f32_16x16x32_bf16(af[mf], bfr[nf],    \
                                                              acc[mf][nf], 0, 0, 0); \
    __builtin_amdgcn_s_setprio(0);                                                \
    __builtin_amdgcn_s_barrier();                                                 \
  }

  // prologue: 3 units in flight; vmcnt(6) -> unit 0 landed (in-order retirement)
  stage(0, 0); stage(1, 1); stage(2, 2);
  asm volatile("s_waitcnt vmcnt(6)" ::: "memory");
  __builtin_amdgcn_s_barrier();

  const int NIT = K >> 7;   // 4 K-halves per iteration
  for (int it = 0; it < NIT; ++it) {
    const int kb = it * 4;
    const int kmax = KH - 1;
    GEMM8_PHASE(0, (kb + 3 < kmax ? kb + 3 : kmax));
    GEMM8_PHASE(1, (kb + 4 < kmax ? kb + 4 : kmax));
    GEMM8_PHASE(2, (kb + 5 < kmax ? kb + 5 : kmax));
    GEMM8_PHASE(3, (kb + 6 < kmax ? kb + 6 : kmax));
  }
#undef GEMM8_PHASE

  const int wr = wm * 64, wc = wn * 64;
#pragma unroll
  for (int mf = 0; mf < 4; ++mf)
#pragma unroll
    for (int nf = 0; nf < 4; ++nf)
#pragma unroll
      for (int r = 0; r < 4; ++r) {
        const int row = brow + wr + mf * 16 + 4 * g + r;
        const int col = bcol + wc + nf * 16 + c;
        C[(size_t)row * N + col] = (OutT)acc[mf][nf][r];
      }
}

// ------------------------------------------- RMSNorm + RoPE epilogues
// q in-place within qkvC: [4096][stride]; output pre-scaled by 1/sqrt(D)*log2(e)
__global__ __launch_bounds__(256) void nrope_q(bf16* __restrict__ q, int stride,
                                               const float* __restrict__ gw,
                                               const float* __restrict__ cache) {
  const float SC = 0.08838834764831845f * 1.4426950408889634f;
  const int w = blockIdx.x * 4 + (threadIdx.x >> 6);
  const int lane = threadIdx.x & 63;
  const int row = w / 24, head = w % 24;
  const int pos = row & 2047;
  bf16* p = q + (size_t)row * stride + head * 128;
  float x1 = (float)p[lane], x2 = (float)p[64 + lane];
  float ss = x1 * x1 + x2 * x2;
#pragma unroll
  for (int m = 32; m; m >>= 1) ss += __shfl_xor(ss, m);
  const float inv = rsqrtf(ss * (1.0f / 128.0f) + 1e-6f);
  const float xn1 = x1 * inv * gw[lane], xn2 = x2 * inv * gw[64 + lane];
  const float cs = cache[pos * 128 + lane] * SC, sn = cache[pos * 128 + 64 + lane] * SC;
  p[lane]      = (bf16)(xn1 * cs - xn2 * sn);
  p[64 + lane] = (bf16)(xn2 * cs + xn1 * sn);
}

// k/tk: src [B*S][stride] (+base col) -> kf [b*8+hkv][2560][128] SWIZZLED (16B slot ^ (key&7))
__global__ __launch_bounds__(256) void nrope_k(const bf16* __restrict__ src, int stride, int base,
                                               bf16* __restrict__ kf,
                                               const float* __restrict__ gw,
                                               const float* __restrict__ cache,
                                               int S, int key_off) {
  const int w = blockIdx.x * 4 + (threadIdx.x >> 6);
  const int lane = threadIdx.x & 63;
  const int row = w >> 3, hkv = w & 7;
  const int b = row / S, s = row % S;
  const bf16* p = src + (size_t)row * stride + base + hkv * 128;
  float x1 = (float)p[lane], x2 = (float)p[64 + lane];
  float ss = x1 * x1 + x2 * x2;
#pragma unroll
  for (int m = 32; m; m >>= 1) ss += __shfl_xor(ss, m);
  const float inv = rsqrtf(ss * (1.0f / 128.0f) + 1e-6f);
  const float xn1 = x1 * inv * gw[lane], xn2 = x2 * inv * gw[64 + lane];
  const float cs = cache[s * 128 + lane], sn = cache[s * 128 + 64 + lane];
  bf16* o = kf + ((size_t)(b * 8 + hkv) * 2560 + key_off + s) * 128;
  const int dsw = lane ^ ((s & 7) << 3);     // key_off is 0 mod 8, so key&7 == s&7
  o[dsw]      = (bf16)(xn1 * cs - xn2 * sn);
  o[64 + dsw] = (bf16)(xn2 * cs + xn1 * sn);
}

// v/tv: src [B*S][stride] (+base col) -> vt [b*8+hkv][128][2560] (transposed, linear)
__global__ __launch_bounds__(256) void transpose_v(const bf16* __restrict__ src, int stride, int base,
                                                   bf16* __restrict__ vtp,
                                                   int S, int key_off) {
  __shared__ bf16 t[32][33];
  const int tid = threadIdx.x;
  const int bh = blockIdx.z;       // b*8+hkv
  const int b = bh >> 3, hkv = bh & 7;
  const int s0 = blockIdx.x * 32, d0 = blockIdx.y * 32;
  const int r = tid >> 3, c4 = (tid & 7) * 4;
  bf16x4 v = *(const bf16x4*)(src + (size_t)(b * S + s0 + r) * stride + base + hkv * 128 + d0 + c4);
  t[r][c4 + 0] = v[0]; t[r][c4 + 1] = v[1]; t[r][c4 + 2] = v[2]; t[r][c4 + 3] = v[3];
  __syncthreads();
  bf16x4 o = { t[c4 + 0][r], t[c4 + 1][r], t[c4 + 2][r], t[c4 + 3][r] };
  *(bf16x4*)(vtp + ((size_t)bh * 128 + d0 + r) * 2560 + key_off + s0 + c4) = o;
}

// ---------------------------------------------------------------- attention (R7, unchanged)
__global__ __launch_bounds__(256, 2) void attn_kernel(const bf16* __restrict__ qf,   // [4096][5120]
                                                      const bf16* __restrict__ kfsw, // [16][2560][128] swz
                                                      const bf16* __restrict__ vtp,  // [16][128][2560]
                                                      bf16* __restrict__ attnb) {    // [4096][3072]
  __shared__ bf16 Ks[2][64 * 128];
  __shared__ bf16 Vs[2][128 * 64];
  __shared__ char Ps[4][1280];
  const int tid = threadIdx.x;
  const int wid = tid >> 6, lane = tid & 63;
  const int g = lane >> 4, c = lane & 15;
  const int bid0 = blockIdx.x;
  const int bid  = (bid0 & 7) * 96 + (bid0 >> 3);
  const int qb = bid & 15;
  const int h  = (bid >> 4) % 24;
  const int b  = bid / 384;
  const int q0 = qb * 128 + wid * 32;
  const int hkv = h / 3;
  const char* kfB = (const char*)kfsw + (size_t)(b * 8 + hkv) * 2560 * 256;
  const char* vtB = (const char*)vtp  + (size_t)(b * 8 + hkv) * 128 * 5120;

  bf16x8 qfrag[2][4];
#pragma unroll
  for (int qt = 0; qt < 2; ++qt) {
    const size_t qrow = (size_t)(b * 2048 + q0 + qt * 16 + c) * 5120 + h * 128;
#pragma unroll
    for (int kc = 0; kc < 4; ++kc)
      qfrag[qt][kc] = *(const bf16x8*)(qf + qrow + kc * 32 + g * 8);
  }

  f32x4 ot[2][8] = {};
  float mrun[2] = { -__builtin_inff(), -__builtin_inff() };
  float lsum[2] = { 0.f, 0.f };

  auto stage = [&](int key0, int buf) {
    {
      char* ldst = (char*)&Ks[buf][0] + wid * 4096;
      const char* gsrc = kfB + (size_t)(key0 + wid * 16) * 256
                       + (lane >> 4) * 256 + (lane & 15) * 16;
#pragma unroll
      for (int j = 0; j < 4; ++j)
        gload16(gsrc + j * 1024, ldst + j * 1024);
    }
    {
      char* ldst = (char*)&Vs[buf][0] + wid * 4096;
      const int r8 = lane >> 3, c8 = lane & 7;
      const char* gsrc = vtB + (size_t)(wid * 32 + r8) * 5120 + (size_t)key0 * 2
                       + ((c8 ^ r8) * 16);
#pragma unroll
      for (int j = 0; j < 4; ++j)
        gload16(gsrc + (size_t)j * 8 * 5120, ldst + j * 1024);
    }
  };

  stage(0, 0);
  __syncthreads();

  for (int it = 0; it < 40; ++it) {
    const int cur = it & 1;
    if (it + 1 < 40) stage((it + 1) * 64, cur ^ 1);

    const char* Kb = (const char*)&Ks[cur][0];
    const char* Vb = (const char*)&Vs[cur][0];

#pragma unroll
    for (int kb = 0; kb < 2; ++kb) {
      f32x4 s[2][2] = {};
      __builtin_amdgcn_s_setprio(1);
#pragma unroll
      for (int kc = 0; kc < 4; ++kc) {
        const int bsw = (kc * 64 + g * 16) ^ ((c & 7) << 4);
        bf16x8 a0 = *(const bf16x8*)(Kb + (kb * 32 + c) * 256 + bsw);
        bf16x8 a1 = *(const bf16x8*)(Kb + (kb * 32 + 16 + c) * 256 + bsw);
#pragma unroll
        for (int qt = 0; qt < 2; ++qt) {
          s[qt][0] = __builtin_amdgcn_mfma_f32_16x16x32_bf16(a0, qfrag[qt][kc], s[qt][0], 0, 0, 0);
          s[qt][1] = __builtin_amdgcn_mfma_f32_16x16x32_bf16(a1, qfrag[qt][kc], s[qt][1], 0, 0, 0);
        }
      }
      __builtin_amdgcn_s_setprio(0);

      bf16x8 vfrag[8];
#pragma unroll
      for (int dt = 0; dt < 8; ++dt)
        vfrag[dt] = *(const bf16x8*)(Vb + (dt * 16 + c) * 128 + (((kb * 4 + g) ^ (c & 7)) * 16));

#pragma unroll
      for (int qt = 0; qt < 2; ++qt) {
        float p0[4], p1[4];
        float tmax = -__builtin_inff();
#pragma unroll
        for (int r = 0; r < 4; ++r) {
          p0[r] = s[qt][0][r];
          p1[r] = s[qt][1][r];
          tmax = fmaxf(tmax, fmaxf(p0[r], p1[r]));
        }
        if (!__all(tmax <= mrun[qt] + 8.f)) {
          tmax = fmaxf(tmax, __shfl_xor(tmax, 16));
          tmax = fmaxf(tmax, __shfl_xor(tmax, 32));
          const float mnew = fmaxf(mrun[qt], tmax);
          const float alpha = fexp2(mrun[qt] - mnew);
          lsum[qt] *= alpha;
#pragma unroll
          for (int dt = 0; dt < 8; ++dt)
#pragma unroll
            for (int r = 0; r < 4; ++r) ot[qt][dt][r] *= alpha;
          mrun[qt] = mnew;
        }
        const float m2 = mrun[qt];
#pragma unroll
        for (int r = 0; r < 4; ++r) {
          p0[r] = fexp2(p0[r] - m2);
          p1[r] = fexp2(p1[r] - m2);
          lsum[qt] += p0[r] + p1[r];
        }
        unsigned* pw = (unsigned*)(&Ps[wid][0] + c * 80);
        pw[2 * g + 0]     = pack2bf(p0[0], p0[1]);
        pw[2 * g + 1]     = pack2bf(p0[2], p0[3]);
        pw[8 + 2 * g + 0] = pack2bf(p1[0], p1[1]);
        pw[8 + 2 * g + 1] = pack2bf(p1[2], p1[3]);
        bf16x8 pf = *(const bf16x8*)(&Ps[wid][0] + c * 80 + g * 16);
        __builtin_amdgcn_s_setprio(1);
#pragma unroll
        for (int dt = 0; dt < 8; ++dt)
          ot[qt][dt] = __builtin_amdgcn_mfma_f32_16x16x32_bf16(vfrag[dt], pf, ot[qt][dt], 0, 0, 0);
        __builtin_amdgcn_s_setprio(0);
      }
    }
    __syncthreads();
  }

  char* osm = (char*)&Ks[0][0] + wid * 8192;
#pragma unroll
  for (int qt = 0; qt < 2; ++qt) {
    float ls = lsum[qt];
    ls += __shfl_xor(ls, 16);
    ls += __shfl_xor(ls, 32);
    const float inv = 1.0f / ls;
    const int q = qt * 16 + c;
#pragma unroll
    for (int dt = 0; dt < 8; ++dt) {
      uint2 w2;
      w2.x = pack2bf(ot[qt][dt][0] * inv, ot[qt][dt][1] * inv);
      w2.y = pack2bf(ot[qt][dt][2] * inv, ot[qt][dt][3] * inv);
      *(uint2*)(osm + q * 256 + ((dt * 32 + 8 * g) ^ ((q & 7) << 4))) = w2;
    }
  }
  __syncthreads();
#pragma unroll
  for (int it = 0; it < 8; ++it) {
    const int off = it * 1024 + lane * 16;
    const int qrow = off >> 8, colb = off & 255;
    bf16x8 v = *(const bf16x8*)(osm + qrow * 256 + (colb ^ ((qrow & 7) << 4)));
    *(bf16x8*)((char*)attnb + ((size_t)(b * 2048 + q0 + qrow) * 3072 + h * 128) * 2 + colb) = v;
  }
}

// ---------------------------------------------------------------- launcher
extern "C" void kernel_launch(void* const* d_in, const int* in_sizes, int n_in,
                              void* d_out, int out_size, void* d_ws, size_t ws_size,
                              hipStream_t stream) {
  const float* hs     = (const float*)d_in[0];
  const float* ehs    = (const float*)d_in[1];
  const float* Wq     = (const float*)d_in[2];
  const float* Wk     = (const float*)d_in[3];
  const float* Wv     = (const float*)d_in[4];
  const float* Wak    = (const float*)d_in[5];
  const float* Wav    = (const float*)d_in[6];
  const float* Wo     = (const float*)d_in[7];
  const float* gq     = (const float*)d_in[8];
  const float* gk     = (const float*)d_in[9];
  const float* gak    = (const float*)d_in[10];
  const float* icache = (const float*)d_in[11];
  const float* tcache = (const float*)d_in[12];

  char* ws = (char*)d_ws;
  bf16* hsb    = (bf16*)(ws + 0);            // 25.2MB; reused as attnb after QKV GEMM
  bf16* Wcomb  = (bf16*)(ws + 25165824);     // [5120][3072] 31.5MB (Wq|Wk|Wv)^T; reused for Wot
  bf16* ehsb   = (bf16*)(ws + 56623104);     // 6.3MB; (ehsb+Wacomb region reused as vt)
  bf16* Wacomb = (bf16*)(ws + 62914560);     // [2048][3072] 12.6MB (Wak|Wav)^T
  bf16* qkvC   = (bf16*)(ws + 75497472);     // [4096][5120] 41.9MB (q|k|v)
  bf16* tC     = (bf16*)(ws + 117440512);    // [1024][2048] 4.2MB (tk|tv)
  bf16* kf     = (bf16*)(ws + 121634816);    // 10.5MB joint K [16][2560][128] (swizzled)
  bf16* Wot    = (bf16*)(ws + 25165824);     // 18.9MB, aliases Wcomb (dead after QKV GEMM)
  bf16* vt     = (bf16*)(ws + 56623104);     // 10.5MB joint V^T, aliases ehsb+Wacomb (dead after tGEMM)
  bf16* attnb  = hsb;                        // aliases hsb (dead after QKV GEMM)

  cvt_bf16<<<6144, 256, 0, stream>>>(hs, hsb, 1572864);
  cvt_bf16<<<1536, 256, 0, stream>>>(ehs, ehsb, 393216);
  tcvt<<<dim3(96, 96), 256, 0, stream>>>(Wq,  Wcomb,                3072, 3072);
  tcvt<<<dim3(32, 96), 256, 0, stream>>>(Wk,  Wcomb + 3072 * 3072,  3072, 1024);
  tcvt<<<dim3(32, 96), 256, 0, stream>>>(Wv,  Wcomb + 4096 * 3072,  3072, 1024);
  tcvt<<<dim3(32, 96), 256, 0, stream>>>(Wak, Wacomb,               3072, 1024);
  tcvt<<<dim3(32, 96), 256, 0, stream>>>(Wav, Wacomb + 1024 * 3072, 3072, 1024);

  // fused QKV GEMM (8-phase): [4096][3072] x [5120][3072]^T -> [4096][5120]
  gemm8<bf16><<<640, 512, 0, stream>>>(hsb, Wcomb, qkvC, 5120, 3072, 20);
  // fused tK/tV GEMM (small): [1024][3072] x [2048][3072]^T -> [1024][2048]
  gemm_bt<bf16><<<dim3(16, 8), 256, 0, stream>>>(ehsb, Wacomb, tC, 2048, 3072);

  // Wo transpose-convert AFTER QKV GEMM (reuses Wcomb region)
  tcvt<<<dim3(96, 96), 256, 0, stream>>>(Wo, Wot, 3072, 3072);

  nrope_q<<<24576, 256, 0, stream>>>(qkvC, 5120, gq, icache);
  nrope_k<<<8192, 256, 0, stream>>>(qkvC, 5120, 3072, kf, gk,  icache, 2048, 0);
  nrope_k<<<2048, 256, 0, stream>>>(tC,   2048, 0,    kf, gak, tcache, 512,  2048);
  transpose_v<<<dim3(64, 4, 16), 256, 0, stream>>>(qkvC, 5120, 4096, vt, 2048, 0);
  transpose_v<<<dim3(16, 4, 16), 256, 0, stream>>>(tC,   2048, 1024, vt, 512,  2048);

  attn_kernel<<<768, 256, 0, stream>>>(qkvC, kf, vt, attnb);

  // out-proj GEMM (8-phase): [4096][3072] x [3072][3072]^T -> fp32 d_out
  gemm8<float><<<384, 512, 0, stream>>>(attnb, Wot, (float*)d_out, 3072, 3072, 12);
}